// Round 1
// baseline (1204.731 us; speedup 1.0000x reference)
//
#include <hip/hip_runtime.h>
#include <math.h>

// Problem constants (match reference)
constexpr int NA = 50000;     // atoms
constexpr int NE = 1600000;   // edges
constexpr int NGR = 250;      // graphs
constexpr int HD = 64;        // hidden = filters
constexpr int NGAUSS = 50;
constexpr int NB = 3;
constexpr float FCUTOFF = 10.0f;

// Wf lookup table
constexpr int NBINS = 8192;
constexpr float TBL_MAX = 8.6603f;             // > 5*sqrt(3) = max possible d
constexpr float TBL_STEP = TBL_MAX / (NBINS - 1);

__device__ __forceinline__ float ssp(float v) {
    // shifted softplus: log(1+e^v) - log(2), numerically stable
    return fmaxf(v, 0.f) + log1pf(expf(-fabsf(v))) - 0.69314718055994530942f;
}

// ---------------- edge prep: d -> fractional bin, payload=(src,fbin), count deg[dst]
__global__ __launch_bounds__(256) void k_edge_prep(const int* __restrict__ ei,
                                                   const float* __restrict__ pos,
                                                   int2* __restrict__ payload,
                                                   int* __restrict__ deg) {
    int e = blockIdx.x * 256 + threadIdx.x;
    if (e >= NE) return;
    int s = ei[e];
    int dt = ei[NE + e];
    float dx = pos[dt * 3 + 0] - pos[s * 3 + 0];
    float dy = pos[dt * 3 + 1] - pos[s * 3 + 1];
    float dz = pos[dt * 3 + 2] - pos[s * 3 + 2];
    float d = sqrtf(dx * dx + dy * dy + dz * dz);
    float fb = d * (1.0f / TBL_STEP);
    fb = fminf(fb, (float)(NBINS - 1) - 1e-3f);   // keep bin <= NBINS-2
    payload[e] = make_int2(s, __float_as_int(fb));
    atomicAdd(&deg[dt], 1);
}

// ---------------- single-block scan of deg -> offsets, cursor
__global__ __launch_bounds__(1024) void k_scan(const int* __restrict__ deg,
                                               int* __restrict__ offsets,
                                               int* __restrict__ cursor) {
    __shared__ int part[1024];
    int tid = threadIdx.x;
    constexpr int CH = (NA + 1023) / 1024;   // 49
    int base = tid * CH;
    int s = 0;
    for (int i = 0; i < CH; i++) {
        int idx = base + i;
        if (idx < NA) s += deg[idx];
    }
    part[tid] = s;
    __syncthreads();
    // Hillis-Steele inclusive scan
    for (int off = 1; off < 1024; off <<= 1) {
        int t = (tid >= off) ? part[tid - off] : 0;
        __syncthreads();
        part[tid] += t;
        __syncthreads();
    }
    int run = part[tid] - s;   // exclusive prefix for this chunk
    for (int i = 0; i < CH; i++) {
        int idx = base + i;
        if (idx < NA) {
            offsets[idx] = run;
            cursor[idx] = run;
            run += deg[idx];
        }
    }
    if (tid == 1023) offsets[NA] = part[1023];
}

// ---------------- scatter edges into dst-buckets
__global__ __launch_bounds__(256) void k_scatter(const int* __restrict__ ei,
                                                 const int2* __restrict__ payload,
                                                 int* __restrict__ cursor,
                                                 int2* __restrict__ spayload) {
    int e = blockIdx.x * 256 + threadIdx.x;
    if (e >= NE) return;
    int dt = ei[NE + e];
    int slot = atomicAdd(&cursor[dt], 1);
    spayload[slot] = payload[e];
}

// ---------------- build Wf tables: tbl[t][bin][f] = (ssp(rbf@w1+b1)@w2+b2)*C(d)
__global__ __launch_bounds__(64) void k_table(const float* __restrict__ w1,
                                              const float* __restrict__ b1,
                                              const float* __restrict__ w2,
                                              const float* __restrict__ b2,
                                              float* __restrict__ tbl) {
    int blk = blockIdx.x;
    int t = blk / NBINS;
    int bin = blk % NBINS;
    int f = threadIdx.x;
    __shared__ float rbf[NGAUSS];
    __shared__ float act[HD];
    float d = bin * TBL_STEP;
    if (f < NGAUSS) {
        float spacing = FCUTOFF / (NGAUSS - 1);
        float off = f * spacing;
        float coeff = -0.5f / (spacing * spacing);
        float u = d - off;
        rbf[f] = expf(coeff * u * u);
    }
    __syncthreads();
    const float* W1 = w1 + t * NGAUSS * HD;
    float a = b1[t * HD + f];
    for (int g = 0; g < NGAUSS; g++) a = fmaf(rbf[g], W1[g * HD + f], a);
    a = ssp(a);
    act[f] = a;
    __syncthreads();
    const float* W2 = w2 + t * HD * HD;
    float o = b2[t * HD + f];
    for (int j = 0; j < HD; j++) o = fmaf(act[j], W2[j * HD + f], o);
    float C = 0.5f * (cosf(d * (float)M_PI / FCUTOFF) + 1.0f);
    tbl[(t * NBINS + bin) * HD + f] = o * C;
}

// ---------------- h init: h = emb[z]
__global__ __launch_bounds__(256) void k_init_h(const int* __restrict__ z,
                                                const float* __restrict__ emb,
                                                float* __restrict__ h) {
    int i = blockIdx.x * 256 + threadIdx.x;
    if (i >= NA * HD) return;
    int n = i >> 6, f = i & 63;
    h[i] = emb[z[n] * HD + f];
}

// ---------------- hx = h @ cf1_w[t]   (row per wave, weights in LDS)
__global__ __launch_bounds__(256) void k_hx(const float* __restrict__ h,
                                            const float* __restrict__ cf1,
                                            float* __restrict__ hx) {
    __shared__ float W[64 * 64];
    for (int i = threadIdx.x; i < 4096; i += 256) W[i] = cf1[i];
    __syncthreads();
    int wave = threadIdx.x >> 6, lane = threadIdx.x & 63;
    int n = blockIdx.x * 4 + wave;
    if (n >= NA) return;
    float v = h[n * 64 + lane];
    float acc = 0.f;
    #pragma unroll
    for (int j = 0; j < 64; j++) acc = fmaf(__shfl(v, j), W[j * 64 + lane], acc);
    hx[n * 64 + lane] = acc;
}

// ---------------- per-node edge aggregation (bucketed gather, no atomics)
__global__ __launch_bounds__(256) void k_edge_agg(const int2* __restrict__ spayload,
                                                  const int* __restrict__ offsets,
                                                  const float* __restrict__ hx,
                                                  const float* __restrict__ tbl_t,
                                                  float* __restrict__ agg) {
    int wave = threadIdx.x >> 6, lane = threadIdx.x & 63;
    int n = blockIdx.x * 4 + wave;
    if (n >= NA) return;
    int start = offsets[n], end = offsets[n + 1];
    float acc = 0.f;
    for (int base = start; base < end; base += 64) {
        int cnt = min(64, end - base);
        int2 p = (base + lane < end) ? spayload[base + lane] : make_int2(0, 0);
        for (int j = 0; j < cnt; j++) {
            int srcn = __shfl(p.x, j);
            float fb = __int_as_float(__shfl(p.y, j));
            int b = (int)fb;
            float fr = fb - (float)b;
            const float* row = tbl_t + b * 64;
            float w0 = row[lane];
            float w1 = row[64 + lane];
            float wf = fmaf(fr, w1 - w0, w0);
            acc = fmaf(wf, hx[srcn * 64 + lane], acc);
        }
    }
    agg[n * 64 + lane] = acc;
}

// ---------------- h += ssp(agg@cf2+b2) @ lin + lb
__global__ __launch_bounds__(256) void k_update(const float* __restrict__ agg,
                                                const float* __restrict__ cf2w,
                                                const float* __restrict__ cf2b,
                                                const float* __restrict__ linw,
                                                const float* __restrict__ linb,
                                                float* __restrict__ h) {
    __shared__ float W2[4096];
    __shared__ float WL[4096];
    for (int i = threadIdx.x; i < 4096; i += 256) {
        W2[i] = cf2w[i];
        WL[i] = linw[i];
    }
    __syncthreads();
    int wave = threadIdx.x >> 6, lane = threadIdx.x & 63;
    int n = blockIdx.x * 4 + wave;
    if (n >= NA) return;
    float v = agg[n * 64 + lane];
    float a = cf2b[lane];
    #pragma unroll
    for (int j = 0; j < 64; j++) a = fmaf(__shfl(v, j), W2[j * 64 + lane], a);
    a = ssp(a);
    float x = linb[lane];
    #pragma unroll
    for (int j = 0; j < 64; j++) x = fmaf(__shfl(a, j), WL[j * 64 + lane], x);
    h[n * 64 + lane] += x;
}

// ---------------- per-graph readout (atomics; g zeroed beforehand)
__global__ __launch_bounds__(256) void k_readout(const float* __restrict__ h,
                                                 const int* __restrict__ batch,
                                                 float* __restrict__ g) {
    int i = blockIdx.x * 256 + threadIdx.x;
    if (i >= NA * HD) return;
    int n = i >> 6, f = i & 63;
    atomicAdd(&g[batch[n] * HD + f], h[i]);
}

// ---------------- head: out = relu(g@o1+b1)@o2+b2
__global__ __launch_bounds__(64) void k_head(const float* __restrict__ g,
                                             const float* __restrict__ o1w,
                                             const float* __restrict__ o1b,
                                             const float* __restrict__ o2w,
                                             const float* __restrict__ o2b,
                                             float* __restrict__ out) {
    int gi = blockIdx.x;
    int lane = threadIdx.x;
    float gv = g[gi * 64 + lane];
    float a = (lane < 32) ? o1b[lane] : 0.f;
    for (int k = 0; k < 64; k++) {
        float w = (lane < 32) ? o1w[k * 32 + lane] : 0.f;
        a = fmaf(__shfl(gv, k), w, a);
    }
    a = fmaxf(a, 0.f);
    float contrib = (lane < 32) ? a * o2w[lane] : 0.f;
    for (int off = 32; off > 0; off >>= 1) contrib += __shfl_down(contrib, off);
    if (lane == 0) out[gi] = contrib + o2b[0];
}

extern "C" void kernel_launch(void* const* d_in, const int* in_sizes, int n_in,
                              void* d_out, int out_size, void* d_ws, size_t ws_size,
                              hipStream_t stream) {
    (void)in_sizes; (void)n_in; (void)out_size; (void)ws_size;
    const int*   z    = (const int*)d_in[0];
    const float* pos  = (const float*)d_in[1];
    const int*   batch= (const int*)d_in[2];
    const int*   ei   = (const int*)d_in[3];
    const float* emb  = (const float*)d_in[4];
    const float* mw1  = (const float*)d_in[5];
    const float* mb1  = (const float*)d_in[6];
    const float* mw2  = (const float*)d_in[7];
    const float* mb2  = (const float*)d_in[8];
    const float* cf1w = (const float*)d_in[9];
    const float* cf2w = (const float*)d_in[10];
    const float* cf2b = (const float*)d_in[11];
    const float* linw = (const float*)d_in[12];
    const float* linb = (const float*)d_in[13];
    const float* o1w  = (const float*)d_in[14];
    const float* o1b  = (const float*)d_in[15];
    const float* o2w  = (const float*)d_in[16];
    const float* o2b  = (const float*)d_in[17];
    float* out = (float*)d_out;

    // workspace carve-up (256B aligned)
    char* w = (char*)d_ws;
    auto take = [&](size_t bytes) {
        char* p = w;
        w += (bytes + 255) & ~size_t(255);
        return p;
    };
    int*   deg      = (int*)take(NA * 4);
    int*   cursor   = (int*)take(NA * 4);
    int*   offsets  = (int*)take((NA + 1) * 4);
    int2*  payload  = (int2*)take((size_t)NE * 8);
    int2*  spayload = (int2*)take((size_t)NE * 8);
    float* tbl      = (float*)take((size_t)NB * NBINS * HD * 4);
    float* h        = (float*)take((size_t)NA * HD * 4);
    float* hx       = (float*)take((size_t)NA * HD * 4);
    float* agg      = (float*)take((size_t)NA * HD * 4);
    float* g        = (float*)take((size_t)NGR * HD * 4);

    hipMemsetAsync(deg, 0, NA * 4, stream);
    hipMemsetAsync(g, 0, NGR * HD * 4, stream);

    k_edge_prep<<<(NE + 255) / 256, 256, 0, stream>>>(ei, pos, payload, deg);
    k_scan<<<1, 1024, 0, stream>>>(deg, offsets, cursor);
    k_scatter<<<(NE + 255) / 256, 256, 0, stream>>>(ei, payload, cursor, spayload);
    k_table<<<NB * NBINS, 64, 0, stream>>>(mw1, mb1, mw2, mb2, tbl);
    k_init_h<<<(NA * HD + 255) / 256, 256, 0, stream>>>(z, emb, h);

    int nodeBlocks = (NA + 3) / 4;
    for (int t = 0; t < NB; t++) {
        k_hx<<<nodeBlocks, 256, 0, stream>>>(h, cf1w + t * 4096, hx);
        k_edge_agg<<<nodeBlocks, 256, 0, stream>>>(spayload, offsets, hx,
                                                   tbl + (size_t)t * NBINS * HD, agg);
        k_update<<<nodeBlocks, 256, 0, stream>>>(agg, cf2w + t * 4096, cf2b + t * 64,
                                                 linw + t * 4096, linb + t * 64, h);
    }
    k_readout<<<(NA * HD + 255) / 256, 256, 0, stream>>>(h, batch, g);
    k_head<<<NGR, 64, 0, stream>>>(g, o1w, o1b, o2w, o2b, out);
}

// Round 2
// 1106.257 us; speedup vs baseline: 1.0890x; 1.0890x over previous
//
#include <hip/hip_runtime.h>
#include <math.h>

// Problem constants (match reference)
constexpr int NA = 50000;     // atoms
constexpr int NE = 1600000;   // edges
constexpr int NGR = 250;      // graphs
constexpr int HD = 64;        // hidden = filters
constexpr int NGAUSS = 50;
constexpr int NB = 3;
constexpr float FCUTOFF = 10.0f;

// Wf lookup table: paired storage tblp[b][f] = {Wf(b*step), Wf((b+1)*step)}
constexpr int NBINS = 4096;
constexpr float TBL_MAX = 8.6603f;             // > 5*sqrt(3) = max possible d
constexpr float TBL_STEP = TBL_MAX / NBINS;

constexpr int SCAN_BLK = 256;
constexpr int SCAN_NB = (NA + SCAN_BLK - 1) / SCAN_BLK;   // 196

__device__ __forceinline__ float ssp(float v) {
    // shifted softplus: log(1+e^v) - log(2), numerically stable
    return fmaxf(v, 0.f) + log1pf(expf(-fabsf(v))) - 0.69314718055994530942f;
}

// ---------------- edge prep: d -> fractional bin, payload=(src,fbin), count deg[dst]
__global__ __launch_bounds__(256) void k_edge_prep(const int* __restrict__ ei,
                                                   const float* __restrict__ pos,
                                                   int2* __restrict__ payload,
                                                   int* __restrict__ deg) {
    int e = blockIdx.x * 256 + threadIdx.x;
    if (e >= NE) return;
    int s = ei[e];
    int dt = ei[NE + e];
    float dx = pos[dt * 3 + 0] - pos[s * 3 + 0];
    float dy = pos[dt * 3 + 1] - pos[s * 3 + 1];
    float dz = pos[dt * 3 + 2] - pos[s * 3 + 2];
    float d = sqrtf(dx * dx + dy * dy + dz * dz);
    float fb = d * (1.0f / TBL_STEP);
    fb = fminf(fb, (float)NBINS - 1e-3f);   // keep bin <= NBINS-1, pair (b,b+1) valid
    payload[e] = make_int2(s, __float_as_int(fb));
    atomicAdd(&deg[dt], 1);
}

// ---------------- 3-phase scan: local exclusive scan per 256-chunk
__global__ __launch_bounds__(SCAN_BLK) void k_scan_local(const int* __restrict__ deg,
                                                         int* __restrict__ offsets,
                                                         int* __restrict__ blocksum) {
    __shared__ int tmp[SCAN_BLK];
    int gid = blockIdx.x * SCAN_BLK + threadIdx.x;
    int v = (gid < NA) ? deg[gid] : 0;
    tmp[threadIdx.x] = v;
    __syncthreads();
    for (int off = 1; off < SCAN_BLK; off <<= 1) {
        int t = (threadIdx.x >= off) ? tmp[threadIdx.x - off] : 0;
        __syncthreads();
        tmp[threadIdx.x] += t;
        __syncthreads();
    }
    if (gid < NA) offsets[gid] = tmp[threadIdx.x] - v;   // local exclusive
    if (threadIdx.x == SCAN_BLK - 1) blocksum[blockIdx.x] = tmp[SCAN_BLK - 1];
}

__global__ __launch_bounds__(256) void k_scan_tops(int* __restrict__ blocksum) {
    __shared__ int tmp[256];
    int v = (threadIdx.x < SCAN_NB) ? blocksum[threadIdx.x] : 0;
    tmp[threadIdx.x] = v;
    __syncthreads();
    for (int off = 1; off < 256; off <<= 1) {
        int t = (threadIdx.x >= off) ? tmp[threadIdx.x - off] : 0;
        __syncthreads();
        tmp[threadIdx.x] += t;
        __syncthreads();
    }
    if (threadIdx.x < SCAN_NB) blocksum[threadIdx.x] = tmp[threadIdx.x] - v;  // exclusive
}

__global__ __launch_bounds__(SCAN_BLK) void k_scan_add(int* __restrict__ offsets,
                                                       const int* __restrict__ blocksum,
                                                       int* __restrict__ cursor) {
    int gid = blockIdx.x * SCAN_BLK + threadIdx.x;
    if (gid < NA) {
        int o = offsets[gid] + blocksum[blockIdx.x];
        offsets[gid] = o;
        cursor[gid] = o;
    }
    if (gid == 0) offsets[NA] = NE;
}

// ---------------- scatter edges into dst-buckets
__global__ __launch_bounds__(256) void k_scatter(const int* __restrict__ ei,
                                                 const int2* __restrict__ payload,
                                                 int* __restrict__ cursor,
                                                 int2* __restrict__ spayload) {
    int e = blockIdx.x * 256 + threadIdx.x;
    if (e >= NE) return;
    int dt = ei[NE + e];
    int slot = atomicAdd(&cursor[dt], 1);
    spayload[slot] = payload[e];
}

// ---------------- build paired Wf tables:
// tblp[t][b][f] = { Wf_t(b*step)[f], Wf_t((b+1)*step)[f] }
__global__ __launch_bounds__(64) void k_table(const float* __restrict__ w1,
                                              const float* __restrict__ b1,
                                              const float* __restrict__ w2,
                                              const float* __restrict__ b2,
                                              float2* __restrict__ tblp) {
    int blk = blockIdx.x;
    int t = blk / NBINS;
    int bin = blk % NBINS;
    int f = threadIdx.x;
    __shared__ float rbf0[NGAUSS], rbf1[NGAUSS];
    __shared__ float act0[HD], act1[HD];
    float d0 = bin * TBL_STEP;
    float d1 = (bin + 1) * TBL_STEP;
    if (f < NGAUSS) {
        float spacing = FCUTOFF / (NGAUSS - 1);
        float off = f * spacing;
        float coeff = -0.5f / (spacing * spacing);
        float u0 = d0 - off, u1 = d1 - off;
        rbf0[f] = expf(coeff * u0 * u0);
        rbf1[f] = expf(coeff * u1 * u1);
    }
    __syncthreads();
    const float* W1 = w1 + t * NGAUSS * HD;
    float a0 = b1[t * HD + f], a1 = a0;
    for (int g = 0; g < NGAUSS; g++) {
        float w = W1[g * HD + f];
        a0 = fmaf(rbf0[g], w, a0);
        a1 = fmaf(rbf1[g], w, a1);
    }
    act0[f] = ssp(a0);
    act1[f] = ssp(a1);
    __syncthreads();
    const float* W2 = w2 + t * HD * HD;
    float o0 = b2[t * HD + f], o1 = o0;
    for (int j = 0; j < HD; j++) {
        float w = W2[j * HD + f];
        o0 = fmaf(act0[j], w, o0);
        o1 = fmaf(act1[j], w, o1);
    }
    float C0 = 0.5f * (cosf(d0 * (float)M_PI / FCUTOFF) + 1.0f);
    float C1 = 0.5f * (cosf(d1 * (float)M_PI / FCUTOFF) + 1.0f);
    tblp[(size_t)(t * NBINS + bin) * HD + f] = make_float2(o0 * C0, o1 * C1);
}

// ---------------- h init: h = emb[z]
__global__ __launch_bounds__(256) void k_init_h(const int* __restrict__ z,
                                                const float* __restrict__ emb,
                                                float* __restrict__ h) {
    int i = blockIdx.x * 256 + threadIdx.x;
    if (i >= NA * HD) return;
    int n = i >> 6, f = i & 63;
    h[i] = emb[z[n] * HD + f];
}

// ---------------- hx = h @ cf1_w[t]   (row per wave, weights in LDS)
__global__ __launch_bounds__(256) void k_hx(const float* __restrict__ h,
                                            const float* __restrict__ cf1,
                                            float* __restrict__ hx) {
    __shared__ float W[64 * 64];
    for (int i = threadIdx.x; i < 4096; i += 256) W[i] = cf1[i];
    __syncthreads();
    int wave = threadIdx.x >> 6, lane = threadIdx.x & 63;
    int n = blockIdx.x * 4 + wave;
    if (n >= NA) return;
    float v = h[n * 64 + lane];
    float acc = 0.f;
    #pragma unroll
    for (int j = 0; j < 64; j++) acc = fmaf(__shfl(v, j), W[j * 64 + lane], acc);
    hx[n * 64 + lane] = acc;
}

// ---------------- per-node edge aggregation (bucketed gather, no atomics)
__global__ __launch_bounds__(256) void k_edge_agg(const int2* __restrict__ spayload,
                                                  const int* __restrict__ offsets,
                                                  const float* __restrict__ hx,
                                                  const float2* __restrict__ tblp_t,
                                                  float* __restrict__ agg) {
    int wave = threadIdx.x >> 6, lane = threadIdx.x & 63;
    int n = blockIdx.x * 4 + wave;
    if (n >= NA) return;
    int start = offsets[n], end = offsets[n + 1];
    float acc = 0.f;
    for (int base = start; base < end; base += 64) {
        int cnt = min(64, end - base);
        int2 p = (base + lane < end) ? spayload[base + lane] : make_int2(0, 0);
        for (int j = 0; j < cnt; j++) {
            int srcn = __builtin_amdgcn_readlane(p.x, j);
            float fb = __int_as_float(__builtin_amdgcn_readlane(p.y, j));
            int b = (int)fb;
            float fr = fb - (float)b;
            float2 w = tblp_t[(size_t)b * 64 + lane];
            float wf = fmaf(fr, w.y - w.x, w.x);
            acc = fmaf(wf, hx[srcn * 64 + lane], acc);
        }
    }
    agg[n * 64 + lane] = acc;
}

// ---------------- h += ssp(agg@cf2+b2) @ lin + lb
__global__ __launch_bounds__(256) void k_update(const float* __restrict__ agg,
                                                const float* __restrict__ cf2w,
                                                const float* __restrict__ cf2b,
                                                const float* __restrict__ linw,
                                                const float* __restrict__ linb,
                                                float* __restrict__ h) {
    __shared__ float W2[4096];
    __shared__ float WL[4096];
    for (int i = threadIdx.x; i < 4096; i += 256) {
        W2[i] = cf2w[i];
        WL[i] = linw[i];
    }
    __syncthreads();
    int wave = threadIdx.x >> 6, lane = threadIdx.x & 63;
    int n = blockIdx.x * 4 + wave;
    if (n >= NA) return;
    float v = agg[n * 64 + lane];
    float a = cf2b[lane];
    #pragma unroll
    for (int j = 0; j < 64; j++) a = fmaf(__shfl(v, j), W2[j * 64 + lane], a);
    a = ssp(a);
    float x = linb[lane];
    #pragma unroll
    for (int j = 0; j < 64; j++) x = fmaf(__shfl(a, j), WL[j * 64 + lane], x);
    h[n * 64 + lane] += x;
}

// ---------------- per-graph readout (atomics; g zeroed beforehand)
__global__ __launch_bounds__(256) void k_readout(const float* __restrict__ h,
                                                 const int* __restrict__ batch,
                                                 float* __restrict__ g) {
    int i = blockIdx.x * 256 + threadIdx.x;
    if (i >= NA * HD) return;
    int n = i >> 6, f = i & 63;
    atomicAdd(&g[batch[n] * HD + f], h[i]);
}

// ---------------- head: out = relu(g@o1+b1)@o2+b2
__global__ __launch_bounds__(64) void k_head(const float* __restrict__ g,
                                             const float* __restrict__ o1w,
                                             const float* __restrict__ o1b,
                                             const float* __restrict__ o2w,
                                             const float* __restrict__ o2b,
                                             float* __restrict__ out) {
    int gi = blockIdx.x;
    int lane = threadIdx.x;
    float gv = g[gi * 64 + lane];
    float a = (lane < 32) ? o1b[lane] : 0.f;
    for (int k = 0; k < 64; k++) {
        float w = (lane < 32) ? o1w[k * 32 + lane] : 0.f;
        a = fmaf(__shfl(gv, k), w, a);
    }
    a = fmaxf(a, 0.f);
    float contrib = (lane < 32) ? a * o2w[lane] : 0.f;
    for (int off = 32; off > 0; off >>= 1) contrib += __shfl_down(contrib, off);
    if (lane == 0) out[gi] = contrib + o2b[0];
}

extern "C" void kernel_launch(void* const* d_in, const int* in_sizes, int n_in,
                              void* d_out, int out_size, void* d_ws, size_t ws_size,
                              hipStream_t stream) {
    (void)in_sizes; (void)n_in; (void)out_size; (void)ws_size;
    const int*   z    = (const int*)d_in[0];
    const float* pos  = (const float*)d_in[1];
    const int*   batch= (const int*)d_in[2];
    const int*   ei   = (const int*)d_in[3];
    const float* emb  = (const float*)d_in[4];
    const float* mw1  = (const float*)d_in[5];
    const float* mb1  = (const float*)d_in[6];
    const float* mw2  = (const float*)d_in[7];
    const float* mb2  = (const float*)d_in[8];
    const float* cf1w = (const float*)d_in[9];
    const float* cf2w = (const float*)d_in[10];
    const float* cf2b = (const float*)d_in[11];
    const float* linw = (const float*)d_in[12];
    const float* linb = (const float*)d_in[13];
    const float* o1w  = (const float*)d_in[14];
    const float* o1b  = (const float*)d_in[15];
    const float* o2w  = (const float*)d_in[16];
    const float* o2b  = (const float*)d_in[17];
    float* out = (float*)d_out;

    // workspace carve-up (256B aligned)
    char* w = (char*)d_ws;
    auto take = [&](size_t bytes) {
        char* p = w;
        w += (bytes + 255) & ~size_t(255);
        return p;
    };
    int*    deg      = (int*)take(NA * 4);
    int*    cursor   = (int*)take(NA * 4);
    int*    offsets  = (int*)take((NA + 1) * 4);
    int*    blocksum = (int*)take(SCAN_NB * 4);
    int2*   payload  = (int2*)take((size_t)NE * 8);
    int2*   spayload = (int2*)take((size_t)NE * 8);
    float2* tblp     = (float2*)take((size_t)NB * NBINS * HD * 8);
    float*  h        = (float*)take((size_t)NA * HD * 4);
    float*  hx       = (float*)take((size_t)NA * HD * 4);
    float*  agg      = (float*)take((size_t)NA * HD * 4);
    float*  g        = (float*)take((size_t)NGR * HD * 4);

    hipMemsetAsync(deg, 0, NA * 4, stream);
    hipMemsetAsync(g, 0, NGR * HD * 4, stream);

    k_edge_prep<<<(NE + 255) / 256, 256, 0, stream>>>(ei, pos, payload, deg);
    k_scan_local<<<SCAN_NB, SCAN_BLK, 0, stream>>>(deg, offsets, blocksum);
    k_scan_tops<<<1, 256, 0, stream>>>(blocksum);
    k_scan_add<<<SCAN_NB, SCAN_BLK, 0, stream>>>(offsets, blocksum, cursor);
    k_scatter<<<(NE + 255) / 256, 256, 0, stream>>>(ei, payload, cursor, spayload);
    k_table<<<NB * NBINS, 64, 0, stream>>>(mw1, mb1, mw2, mb2, tblp);
    k_init_h<<<(NA * HD + 255) / 256, 256, 0, stream>>>(z, emb, h);

    int nodeBlocks = (NA + 3) / 4;
    for (int t = 0; t < NB; t++) {
        k_hx<<<nodeBlocks, 256, 0, stream>>>(h, cf1w + t * 4096, hx);
        k_edge_agg<<<nodeBlocks, 256, 0, stream>>>(spayload, offsets, hx,
                                                   tblp + (size_t)t * NBINS * HD, agg);
        k_update<<<nodeBlocks, 256, 0, stream>>>(agg, cf2w + t * 4096, cf2b + t * 64,
                                                 linw + t * 4096, linb + t * 64, h);
    }
    k_readout<<<(NA * HD + 255) / 256, 256, 0, stream>>>(h, batch, g);
    k_head<<<NGR, 64, 0, stream>>>(g, o1w, o1b, o2w, o2b, out);
}

// Round 3
// 957.880 us; speedup vs baseline: 1.2577x; 1.1549x over previous
//
#include <hip/hip_runtime.h>
#include <math.h>

// Problem constants (match reference)
constexpr int NA = 50000;     // atoms
constexpr int NE = 1600000;   // edges
constexpr int NGR = 250;      // graphs
constexpr int HD = 64;        // hidden = filters
constexpr int NGAUSS = 50;
constexpr int NB = 3;
constexpr float FCUTOFF = 10.0f;

// Wf lookup table: paired storage tblp[b][f] = {Wf(b*step), Wf((b+1)*step)}
constexpr int NBINS = 4096;
constexpr float TBL_MAX = 8.6603f;             // > 5*sqrt(3) = max possible d
constexpr float TBL_STEP = TBL_MAX / NBINS;

constexpr int NBKT = (NA + 255) / 256;         // 196 coarse buckets (dst>>8)
constexpr int S1_EPB = 4096;                   // edges per sort-pass-1 block
constexpr int S1_NB = (NE + S1_EPB - 1) / S1_EPB;   // 391

__device__ __forceinline__ float ssp(float v) {
    return fmaxf(v, 0.f) + log1pf(expf(-fabsf(v))) - 0.69314718055994530942f;
}

// ---------------- coarse histogram of dst>>8
__global__ __launch_bounds__(1024) void k_count(const int* __restrict__ ei,
                                                int* __restrict__ hist1) {
    __shared__ int lh[NBKT];
    for (int i = threadIdx.x; i < NBKT; i += 1024) lh[i] = 0;
    __syncthreads();
    int base = blockIdx.x * S1_EPB;
    #pragma unroll
    for (int i = 0; i < 4; i++) {
        int e = base + i * 1024 + threadIdx.x;
        if (e < NE) atomicAdd(&lh[ei[NE + e] >> 8], 1);
    }
    __syncthreads();
    for (int i = threadIdx.x; i < NBKT; i += 1024)
        if (lh[i]) atomicAdd(&hist1[i], lh[i]);
}

// ---------------- scan 196 coarse counts -> offsets1, gcursor1; fixups
__global__ __launch_bounds__(256) void k_scan196(const int* __restrict__ hist1,
                                                 int* __restrict__ offsets1,
                                                 int* __restrict__ gcursor1,
                                                 int* __restrict__ offsets) {
    __shared__ int buf[256];
    int tid = threadIdx.x;
    int v = (tid < NBKT) ? hist1[tid] : 0;
    buf[tid] = v;
    __syncthreads();
    for (int off = 1; off < 256; off <<= 1) {
        int t = (tid >= off) ? buf[tid - off] : 0;
        __syncthreads();
        buf[tid] += t;
        __syncthreads();
    }
    int excl = buf[tid] - v;
    if (tid < NBKT) { offsets1[tid] = excl; gcursor1[tid] = excl; }
    if (tid == NBKT - 1) offsets1[NBKT] = excl + v;   // == NE
    if (tid == 0) offsets[NA] = NE;
}

// ---------------- sort pass 1: fused edge prep + coarse-bucket grouping.
// record: .x = src | (dst&255)<<17 ; .y = fbin (float bits)
__global__ __launch_bounds__(1024) void k_sort1(const int* __restrict__ ei,
                                                const float* __restrict__ pos,
                                                int* __restrict__ gcursor1,
                                                int2* __restrict__ brec) {
    __shared__ int2 recs[S1_EPB];
    __shared__ unsigned char rbkt[S1_EPB];
    __shared__ int hist[NBKT];
    __shared__ int lcur[NBKT];
    __shared__ int delta[NBKT];
    __shared__ int scanbuf[256];
    int tid = threadIdx.x;
    for (int i = tid; i < NBKT; i += 1024) hist[i] = 0;
    __syncthreads();
    int2 myrec[4];
    int mybkt[4];
    int base = blockIdx.x * S1_EPB;
    #pragma unroll
    for (int i = 0; i < 4; i++) {
        int e = base + i * 1024 + tid;
        mybkt[i] = -1;
        if (e < NE) {
            int s = ei[e];
            int dt = ei[NE + e];
            float dx = pos[dt * 3 + 0] - pos[s * 3 + 0];
            float dy = pos[dt * 3 + 1] - pos[s * 3 + 1];
            float dz = pos[dt * 3 + 2] - pos[s * 3 + 2];
            float d = sqrtf(dx * dx + dy * dy + dz * dz);
            float fb = fminf(d * (1.0f / TBL_STEP), (float)NBINS - 1e-3f);
            myrec[i] = make_int2(s | ((dt & 255) << 17), __float_as_int(fb));
            mybkt[i] = dt >> 8;
            atomicAdd(&hist[mybkt[i]], 1);
        }
    }
    __syncthreads();
    // exclusive scan of hist over 256 slots
    int v = (tid < NBKT) ? hist[tid] : 0;
    if (tid < 256) scanbuf[tid] = v;
    __syncthreads();
    for (int off = 1; off < 256; off <<= 1) {
        int t = (tid >= off && tid < 256) ? scanbuf[tid - off] : 0;
        __syncthreads();
        if (tid < 256) scanbuf[tid] += t;
        __syncthreads();
    }
    if (tid < NBKT) {
        int excl = scanbuf[tid] - v;
        lcur[tid] = excl;
        int gbase = atomicAdd(&gcursor1[tid], v);
        delta[tid] = gbase - excl;
    }
    __syncthreads();
    #pragma unroll
    for (int i = 0; i < 4; i++) {
        if (mybkt[i] >= 0) {
            int r = atomicAdd(&lcur[mybkt[i]], 1);
            recs[r] = myrec[i];
            rbkt[r] = (unsigned char)mybkt[i];
        }
    }
    __syncthreads();
    int total = min(S1_EPB, NE - base);
    for (int p = tid; p < total; p += 1024)
        brec[delta[rbkt[p]] + p] = recs[p];
}

// ---------------- sort pass 2: one block per coarse bucket.
// Ranks records by node via LDS, writes final node-sorted payload AND offsets[].
__global__ __launch_bounds__(1024) void k_sort2(const int2* __restrict__ brec,
                                                const int* __restrict__ offsets1,
                                                int2* __restrict__ spayload,
                                                int* __restrict__ offsets) {
    __shared__ int cnt[256];
    __shared__ int lstart[256];
    __shared__ int lcur[256];
    int b = blockIdx.x;
    int tid = threadIdx.x;
    if (tid < 256) cnt[tid] = 0;
    __syncthreads();
    int rbase = offsets1[b], rend = offsets1[b + 1];
    for (int p = rbase + tid; p < rend; p += 1024)
        atomicAdd(&cnt[(brec[p].x >> 17) & 255], 1);
    __syncthreads();
    int v = (tid < 256) ? cnt[tid] : 0;
    if (tid < 256) lstart[tid] = v;
    __syncthreads();
    for (int off = 1; off < 256; off <<= 1) {
        int t = (tid >= off && tid < 256) ? lstart[tid - off] : 0;
        __syncthreads();
        if (tid < 256) lstart[tid] += t;
        __syncthreads();
    }
    if (tid < 256) {
        lstart[tid] -= v;                 // exclusive
        lcur[tid] = rbase + lstart[tid];  // global cursor for this node
        int node = (b << 8) + tid;
        if (node < NA) offsets[node] = rbase + lstart[tid];
    }
    __syncthreads();
    for (int p = rbase + tid; p < rend; p += 1024) {
        int2 r = brec[p];
        int slot = atomicAdd(&lcur[(r.x >> 17) & 255], 1);
        spayload[slot] = r;
    }
}

// ---------------- build paired Wf tables
__global__ __launch_bounds__(64) void k_table(const float* __restrict__ w1,
                                              const float* __restrict__ b1,
                                              const float* __restrict__ w2,
                                              const float* __restrict__ b2,
                                              float2* __restrict__ tblp) {
    int blk = blockIdx.x;
    int t = blk / NBINS;
    int bin = blk % NBINS;
    int f = threadIdx.x;
    __shared__ float rbf0[NGAUSS], rbf1[NGAUSS];
    __shared__ float act0[HD], act1[HD];
    float d0 = bin * TBL_STEP;
    float d1 = (bin + 1) * TBL_STEP;
    if (f < NGAUSS) {
        float spacing = FCUTOFF / (NGAUSS - 1);
        float off = f * spacing;
        float coeff = -0.5f / (spacing * spacing);
        float u0 = d0 - off, u1 = d1 - off;
        rbf0[f] = expf(coeff * u0 * u0);
        rbf1[f] = expf(coeff * u1 * u1);
    }
    __syncthreads();
    const float* W1 = w1 + t * NGAUSS * HD;
    float a0 = b1[t * HD + f], a1 = a0;
    for (int g = 0; g < NGAUSS; g++) {
        float w = W1[g * HD + f];
        a0 = fmaf(rbf0[g], w, a0);
        a1 = fmaf(rbf1[g], w, a1);
    }
    act0[f] = ssp(a0);
    act1[f] = ssp(a1);
    __syncthreads();
    const float* W2 = w2 + t * HD * HD;
    float o0 = b2[t * HD + f], o1 = o0;
    for (int j = 0; j < HD; j++) {
        float w = W2[j * HD + f];
        o0 = fmaf(act0[j], w, o0);
        o1 = fmaf(act1[j], w, o1);
    }
    float C0 = 0.5f * (cosf(d0 * (float)M_PI / FCUTOFF) + 1.0f);
    float C1 = 0.5f * (cosf(d1 * (float)M_PI / FCUTOFF) + 1.0f);
    tblp[(size_t)(t * NBINS + bin) * HD + f] = make_float2(o0 * C0, o1 * C1);
}

// ---------------- h init: h = emb[z]
__global__ __launch_bounds__(256) void k_init_h(const int* __restrict__ z,
                                                const float* __restrict__ emb,
                                                float* __restrict__ h) {
    int i = blockIdx.x * 256 + threadIdx.x;
    if (i >= NA * HD) return;
    int n = i >> 6, f = i & 63;
    h[i] = emb[z[n] * HD + f];
}

// ---------------- hx = h @ cf1_w[t]
__global__ __launch_bounds__(256) void k_hx(const float* __restrict__ h,
                                            const float* __restrict__ cf1,
                                            float* __restrict__ hx) {
    __shared__ float W[64 * 64];
    for (int i = threadIdx.x; i < 4096; i += 256) W[i] = cf1[i];
    __syncthreads();
    int wave = threadIdx.x >> 6, lane = threadIdx.x & 63;
    int n = blockIdx.x * 4 + wave;
    if (n >= NA) return;
    float v = h[n * 64 + lane];
    float acc = 0.f;
    #pragma unroll
    for (int j = 0; j < 64; j++) acc = fmaf(__shfl(v, j), W[j * 64 + lane], acc);
    hx[n * 64 + lane] = acc;
}

// ---------------- per-node edge aggregation (bucketed gather, no atomics)
__global__ __launch_bounds__(256) void k_edge_agg(const int2* __restrict__ spayload,
                                                  const int* __restrict__ offsets,
                                                  const float* __restrict__ hx,
                                                  const float2* __restrict__ tblp_t,
                                                  float* __restrict__ agg) {
    int wave = threadIdx.x >> 6, lane = threadIdx.x & 63;
    int n = blockIdx.x * 4 + wave;
    if (n >= NA) return;
    int start = offsets[n], end = offsets[n + 1];
    float acc = 0.f;
    for (int base = start; base < end; base += 64) {
        int cnt = min(64, end - base);
        int2 p = (base + lane < end) ? spayload[base + lane] : make_int2(0, 0);
        for (int j = 0; j < cnt; j++) {
            int srcn = __builtin_amdgcn_readlane(p.x, j) & 0x1FFFF;
            float fb = __int_as_float(__builtin_amdgcn_readlane(p.y, j));
            int b = (int)fb;
            float fr = fb - (float)b;
            float2 w = tblp_t[(size_t)b * 64 + lane];
            float wf = fmaf(fr, w.y - w.x, w.x);
            acc = fmaf(wf, hx[srcn * 64 + lane], acc);
        }
    }
    agg[n * 64 + lane] = acc;
}

// ---------------- h += ssp(agg@cf2+b2) @ lin + lb
__global__ __launch_bounds__(256) void k_update(const float* __restrict__ agg,
                                                const float* __restrict__ cf2w,
                                                const float* __restrict__ cf2b,
                                                const float* __restrict__ linw,
                                                const float* __restrict__ linb,
                                                float* __restrict__ h) {
    __shared__ float W2[4096];
    __shared__ float WL[4096];
    for (int i = threadIdx.x; i < 4096; i += 256) {
        W2[i] = cf2w[i];
        WL[i] = linw[i];
    }
    __syncthreads();
    int wave = threadIdx.x >> 6, lane = threadIdx.x & 63;
    int n = blockIdx.x * 4 + wave;
    if (n >= NA) return;
    float v = agg[n * 64 + lane];
    float a = cf2b[lane];
    #pragma unroll
    for (int j = 0; j < 64; j++) a = fmaf(__shfl(v, j), W2[j * 64 + lane], a);
    a = ssp(a);
    float x = linb[lane];
    #pragma unroll
    for (int j = 0; j < 64; j++) x = fmaf(__shfl(a, j), WL[j * 64 + lane], x);
    h[n * 64 + lane] += x;
}

// ---------------- per-graph readout
__global__ __launch_bounds__(256) void k_readout(const float* __restrict__ h,
                                                 const int* __restrict__ batch,
                                                 float* __restrict__ g) {
    int i = blockIdx.x * 256 + threadIdx.x;
    if (i >= NA * HD) return;
    int n = i >> 6, f = i & 63;
    atomicAdd(&g[batch[n] * HD + f], h[i]);
}

// ---------------- head
__global__ __launch_bounds__(64) void k_head(const float* __restrict__ g,
                                             const float* __restrict__ o1w,
                                             const float* __restrict__ o1b,
                                             const float* __restrict__ o2w,
                                             const float* __restrict__ o2b,
                                             float* __restrict__ out) {
    int gi = blockIdx.x;
    int lane = threadIdx.x;
    float gv = g[gi * 64 + lane];
    float a = (lane < 32) ? o1b[lane] : 0.f;
    for (int k = 0; k < 64; k++) {
        float w = (lane < 32) ? o1w[k * 32 + lane] : 0.f;
        a = fmaf(__shfl(gv, k), w, a);
    }
    a = fmaxf(a, 0.f);
    float contrib = (lane < 32) ? a * o2w[lane] : 0.f;
    for (int off = 32; off > 0; off >>= 1) contrib += __shfl_down(contrib, off);
    if (lane == 0) out[gi] = contrib + o2b[0];
}

extern "C" void kernel_launch(void* const* d_in, const int* in_sizes, int n_in,
                              void* d_out, int out_size, void* d_ws, size_t ws_size,
                              hipStream_t stream) {
    (void)in_sizes; (void)n_in; (void)out_size; (void)ws_size;
    const int*   z    = (const int*)d_in[0];
    const float* pos  = (const float*)d_in[1];
    const int*   batch= (const int*)d_in[2];
    const int*   ei   = (const int*)d_in[3];
    const float* emb  = (const float*)d_in[4];
    const float* mw1  = (const float*)d_in[5];
    const float* mb1  = (const float*)d_in[6];
    const float* mw2  = (const float*)d_in[7];
    const float* mb2  = (const float*)d_in[8];
    const float* cf1w = (const float*)d_in[9];
    const float* cf2w = (const float*)d_in[10];
    const float* cf2b = (const float*)d_in[11];
    const float* linw = (const float*)d_in[12];
    const float* linb = (const float*)d_in[13];
    const float* o1w  = (const float*)d_in[14];
    const float* o1b  = (const float*)d_in[15];
    const float* o2w  = (const float*)d_in[16];
    const float* o2b  = (const float*)d_in[17];
    float* out = (float*)d_out;

    char* w = (char*)d_ws;
    auto take = [&](size_t bytes) {
        char* p = w;
        w += (bytes + 255) & ~size_t(255);
        return p;
    };
    int*    hist1    = (int*)take(NBKT * 4);
    int*    offsets1 = (int*)take((NBKT + 1) * 4);
    int*    gcursor1 = (int*)take(NBKT * 4);
    int*    offsets  = (int*)take((NA + 1) * 4);
    int2*   brec     = (int2*)take((size_t)NE * 8);
    int2*   spayload = (int2*)take((size_t)NE * 8);
    float2* tblp     = (float2*)take((size_t)NB * NBINS * HD * 8);
    float*  h        = (float*)take((size_t)NA * HD * 4);
    float*  hx       = (float*)take((size_t)NA * HD * 4);
    float*  agg      = (float*)take((size_t)NA * HD * 4);
    float*  g        = (float*)take((size_t)NGR * HD * 4);

    hipMemsetAsync(hist1, 0, NBKT * 4, stream);
    hipMemsetAsync(g, 0, NGR * HD * 4, stream);

    k_count<<<S1_NB, 1024, 0, stream>>>(ei, hist1);
    k_scan196<<<1, 256, 0, stream>>>(hist1, offsets1, gcursor1, offsets);
    k_sort1<<<S1_NB, 1024, 0, stream>>>(ei, pos, gcursor1, brec);
    k_sort2<<<NBKT, 1024, 0, stream>>>(brec, offsets1, spayload, offsets);
    k_table<<<NB * NBINS, 64, 0, stream>>>(mw1, mb1, mw2, mb2, tblp);
    k_init_h<<<(NA * HD + 255) / 256, 256, 0, stream>>>(z, emb, h);

    int nodeBlocks = (NA + 3) / 4;
    for (int t = 0; t < NB; t++) {
        k_hx<<<nodeBlocks, 256, 0, stream>>>(h, cf1w + t * 4096, hx);
        k_edge_agg<<<nodeBlocks, 256, 0, stream>>>(spayload, offsets, hx,
                                                   tblp + (size_t)t * NBINS * HD, agg);
        k_update<<<nodeBlocks, 256, 0, stream>>>(agg, cf2w + t * 4096, cf2b + t * 64,
                                                 linw + t * 4096, linb + t * 64, h);
    }
    k_readout<<<(NA * HD + 255) / 256, 256, 0, stream>>>(h, batch, g);
    k_head<<<NGR, 64, 0, stream>>>(g, o1w, o1b, o2w, o2b, out);
}

// Round 4
// 600.352 us; speedup vs baseline: 2.0067x; 1.5955x over previous
//
#include <hip/hip_runtime.h>
#include <math.h>

constexpr int NA = 50000;
constexpr int NE = 1600000;
constexpr int NGR = 250;
constexpr int HD = 64;
constexpr int NGAUSS = 50;
constexpr int NB = 3;
constexpr float FCUTOFF = 10.0f;

constexpr int NBINS = 4096;
constexpr float TBL_MAX = 8.6603f;
constexpr float TBL_STEP = TBL_MAX / NBINS;

constexpr int NBKT = (NA + 255) / 256;              // 196
constexpr int S1_EPB = 4096;
constexpr int S1_NB = (NE + S1_EPB - 1) / S1_EPB;   // 391

constexpr int NTILE = NA / 16;                      // 3125 (exact)
constexpr int MM_NB = (NTILE + 3) / 4;              // 782

typedef __attribute__((ext_vector_type(8))) short short8;
typedef __attribute__((ext_vector_type(4))) float floatx4;
typedef unsigned int uint;
typedef unsigned short ushort;

__device__ __forceinline__ float ssp(float v) {
    return fmaxf(v, 0.f) + log1pf(expf(-fabsf(v))) - 0.69314718055994530942f;
}
__device__ __forceinline__ ushort f2bf(float f) {
    uint u = __float_as_uint(f);
    return (ushort)((u + 0x7fffu + ((u >> 16) & 1u)) >> 16);   // RNE
}
__device__ __forceinline__ float bf2f(ushort h) {
    return __uint_as_float(((uint)h) << 16);
}

// ================= sort pipeline (unchanged from R3) =================
__global__ __launch_bounds__(1024) void k_count(const int* __restrict__ ei,
                                                int* __restrict__ hist1) {
    __shared__ int lh[NBKT];
    for (int i = threadIdx.x; i < NBKT; i += 1024) lh[i] = 0;
    __syncthreads();
    int base = blockIdx.x * S1_EPB;
    #pragma unroll
    for (int i = 0; i < 4; i++) {
        int e = base + i * 1024 + threadIdx.x;
        if (e < NE) atomicAdd(&lh[ei[NE + e] >> 8], 1);
    }
    __syncthreads();
    for (int i = threadIdx.x; i < NBKT; i += 1024)
        if (lh[i]) atomicAdd(&hist1[i], lh[i]);
}

__global__ __launch_bounds__(256) void k_scan196(const int* __restrict__ hist1,
                                                 int* __restrict__ offsets1,
                                                 int* __restrict__ gcursor1,
                                                 int* __restrict__ offsets) {
    __shared__ int buf[256];
    int tid = threadIdx.x;
    int v = (tid < NBKT) ? hist1[tid] : 0;
    buf[tid] = v;
    __syncthreads();
    for (int off = 1; off < 256; off <<= 1) {
        int t = (tid >= off) ? buf[tid - off] : 0;
        __syncthreads();
        buf[tid] += t;
        __syncthreads();
    }
    int excl = buf[tid] - v;
    if (tid < NBKT) { offsets1[tid] = excl; gcursor1[tid] = excl; }
    if (tid == NBKT - 1) offsets1[NBKT] = excl + v;
    if (tid == 0) offsets[NA] = NE;
}

__global__ __launch_bounds__(1024) void k_sort1(const int* __restrict__ ei,
                                                const float* __restrict__ pos,
                                                int* __restrict__ gcursor1,
                                                int2* __restrict__ brec) {
    __shared__ int2 recs[S1_EPB];
    __shared__ unsigned char rbkt[S1_EPB];
    __shared__ int hist[NBKT];
    __shared__ int lcur[NBKT];
    __shared__ int delta[NBKT];
    __shared__ int scanbuf[256];
    int tid = threadIdx.x;
    for (int i = tid; i < NBKT; i += 1024) hist[i] = 0;
    __syncthreads();
    int2 myrec[4];
    int mybkt[4];
    int base = blockIdx.x * S1_EPB;
    #pragma unroll
    for (int i = 0; i < 4; i++) {
        int e = base + i * 1024 + tid;
        mybkt[i] = -1;
        if (e < NE) {
            int s = ei[e];
            int dt = ei[NE + e];
            float dx = pos[dt * 3 + 0] - pos[s * 3 + 0];
            float dy = pos[dt * 3 + 1] - pos[s * 3 + 1];
            float dz = pos[dt * 3 + 2] - pos[s * 3 + 2];
            float d = sqrtf(dx * dx + dy * dy + dz * dz);
            float fb = fminf(d * (1.0f / TBL_STEP), (float)NBINS - 1e-3f);
            myrec[i] = make_int2(s | ((dt & 255) << 17), __float_as_int(fb));
            mybkt[i] = dt >> 8;
            atomicAdd(&hist[mybkt[i]], 1);
        }
    }
    __syncthreads();
    int v = (tid < NBKT) ? hist[tid] : 0;
    if (tid < 256) scanbuf[tid] = v;
    __syncthreads();
    for (int off = 1; off < 256; off <<= 1) {
        int t = (tid >= off && tid < 256) ? scanbuf[tid - off] : 0;
        __syncthreads();
        if (tid < 256) scanbuf[tid] += t;
        __syncthreads();
    }
    if (tid < NBKT) {
        int excl = scanbuf[tid] - v;
        lcur[tid] = excl;
        int gbase = atomicAdd(&gcursor1[tid], v);
        delta[tid] = gbase - excl;
    }
    __syncthreads();
    #pragma unroll
    for (int i = 0; i < 4; i++) {
        if (mybkt[i] >= 0) {
            int r = atomicAdd(&lcur[mybkt[i]], 1);
            recs[r] = myrec[i];
            rbkt[r] = (unsigned char)mybkt[i];
        }
    }
    __syncthreads();
    int total = min(S1_EPB, NE - base);
    for (int p = tid; p < total; p += 1024)
        brec[delta[rbkt[p]] + p] = recs[p];
}

__global__ __launch_bounds__(1024) void k_sort2(const int2* __restrict__ brec,
                                                const int* __restrict__ offsets1,
                                                int2* __restrict__ spayload,
                                                int* __restrict__ offsets) {
    __shared__ int cnt[256];
    __shared__ int lstart[256];
    __shared__ int lcur[256];
    int b = blockIdx.x;
    int tid = threadIdx.x;
    if (tid < 256) cnt[tid] = 0;
    __syncthreads();
    int rbase = offsets1[b], rend = offsets1[b + 1];
    for (int p = rbase + tid; p < rend; p += 1024)
        atomicAdd(&cnt[(brec[p].x >> 17) & 255], 1);
    __syncthreads();
    int v = (tid < 256) ? cnt[tid] : 0;
    if (tid < 256) lstart[tid] = v;
    __syncthreads();
    for (int off = 1; off < 256; off <<= 1) {
        int t = (tid >= off && tid < 256) ? lstart[tid - off] : 0;
        __syncthreads();
        if (tid < 256) lstart[tid] += t;
        __syncthreads();
    }
    if (tid < 256) {
        lstart[tid] -= v;
        lcur[tid] = rbase + lstart[tid];
        int node = (b << 8) + tid;
        if (node < NA) offsets[node] = rbase + lstart[tid];
    }
    __syncthreads();
    for (int p = rbase + tid; p < rend; p += 1024) {
        int2 r = brec[p];
        int slot = atomicAdd(&lcur[(r.x >> 17) & 255], 1);
        spayload[slot] = r;
    }
}

// ================= Wf table, packed bf16 pair per (bin, channel) =================
__global__ __launch_bounds__(64) void k_table(const float* __restrict__ w1,
                                              const float* __restrict__ b1,
                                              const float* __restrict__ w2,
                                              const float* __restrict__ b2,
                                              uint* __restrict__ tblb) {
    int blk = blockIdx.x;
    int t = blk / NBINS;
    int bin = blk % NBINS;
    int f = threadIdx.x;
    __shared__ float rbf0[NGAUSS], rbf1[NGAUSS];
    __shared__ float act0[HD], act1[HD];
    float d0 = bin * TBL_STEP;
    float d1 = (bin + 1) * TBL_STEP;
    if (f < NGAUSS) {
        float spacing = FCUTOFF / (NGAUSS - 1);
        float off = f * spacing;
        float coeff = -0.5f / (spacing * spacing);
        float u0 = d0 - off, u1 = d1 - off;
        rbf0[f] = expf(coeff * u0 * u0);
        rbf1[f] = expf(coeff * u1 * u1);
    }
    __syncthreads();
    const float* W1 = w1 + t * NGAUSS * HD;
    float a0 = b1[t * HD + f], a1 = a0;
    for (int g = 0; g < NGAUSS; g++) {
        float w = W1[g * HD + f];
        a0 = fmaf(rbf0[g], w, a0);
        a1 = fmaf(rbf1[g], w, a1);
    }
    act0[f] = ssp(a0);
    act1[f] = ssp(a1);
    __syncthreads();
    const float* W2 = w2 + t * HD * HD;
    float o0 = b2[t * HD + f], o1 = o0;
    for (int j = 0; j < HD; j++) {
        float w = W2[j * HD + f];
        o0 = fmaf(act0[j], w, o0);
        o1 = fmaf(act1[j], w, o1);
    }
    float C0 = 0.5f * (cosf(d0 * (float)M_PI / FCUTOFF) + 1.0f);
    float C1 = 0.5f * (cosf(d1 * (float)M_PI / FCUTOFF) + 1.0f);
    tblb[(size_t)(t * NBINS + bin) * HD + f] =
        ((uint)f2bf(o1 * C1) << 16) | (uint)f2bf(o0 * C0);
}

// ================= weight prep: bf16 hi/lo in B-fragment order [mat][n][k] =====
__global__ __launch_bounds__(256) void k_wprep(const float* __restrict__ cf1w,
                                               const float* __restrict__ cf2w,
                                               const float* __restrict__ linw,
                                               ushort* __restrict__ whi,
                                               ushort* __restrict__ wlo) {
    int idx = blockIdx.x * 256 + threadIdx.x;   // 9*4096
    if (idx >= 9 * 4096) return;
    int mi = idx >> 12;
    int t = mi / 3, which = mi % 3;
    int rem = idx & 4095;
    int n = rem >> 6, k = rem & 63;
    const float* src = (which == 0) ? cf1w : (which == 1) ? cf2w : linw;
    float v = src[t * 4096 + k * 64 + n];
    ushort hi = f2bf(v);
    ushort lo = f2bf(v - bf2f(hi));
    whi[mi * 4096 + n * 64 + k] = hi;
    wlo[mi * 4096 + n * 64 + k] = lo;
}

// ================= h init =================
__global__ __launch_bounds__(256) void k_init_h(const int* __restrict__ z,
                                                const float* __restrict__ emb,
                                                float* __restrict__ h) {
    int i = blockIdx.x * 256 + threadIdx.x;
    if (i >= NA * HD) return;
    int n = i >> 6, f = i & 63;
    h[i] = emb[z[n] * HD + f];
}

// helper: build hi/lo A-fragments from 8 consecutive fp32
__device__ __forceinline__ void mk_frag(const float* p, short8& hi, short8& lo) {
    float4 a0 = *(const float4*)p;
    float4 a1 = *(const float4*)(p + 4);
    float av[8] = {a0.x, a0.y, a0.z, a0.w, a1.x, a1.y, a1.z, a1.w};
    #pragma unroll
    for (int j = 0; j < 8; j++) {
        ushort h = f2bf(av[j]);
        hi[j] = (short)h;
        lo[j] = (short)f2bf(av[j] - bf2f(h));
    }
}

// ================= hx = h @ cf1  (MFMA, fp32-accurate via hi/lo split) ==========
// output hx in bf16 for the edge kernel
__global__ __launch_bounds__(256) void k_hx(const float* __restrict__ h,
                                            const ushort* __restrict__ whi_m,
                                            const ushort* __restrict__ wlo_m,
                                            ushort* __restrict__ hxb) {
    int wave = threadIdx.x >> 6, lane = threadIdx.x & 63;
    int tile = blockIdx.x * 4 + wave;
    if (tile >= NTILE) return;
    int m0 = tile * 16;
    int q = lane >> 4, ln = lane & 15;

    short8 ah[2], al[2];
    #pragma unroll
    for (int ks = 0; ks < 2; ks++)
        mk_frag(h + (m0 + ln) * 64 + ks * 32 + q * 8, ah[ks], al[ks]);

    floatx4 acc[4];
    #pragma unroll
    for (int nt = 0; nt < 4; nt++) acc[nt] = (floatx4){0.f, 0.f, 0.f, 0.f};

    #pragma unroll
    for (int ks = 0; ks < 2; ks++) {
        #pragma unroll
        for (int nt = 0; nt < 4; nt++) {
            int off = (nt * 16 + ln) * 64 + ks * 32 + q * 8;
            short8 bh = *(const short8*)(whi_m + off);
            short8 bl = *(const short8*)(wlo_m + off);
            acc[nt] = __builtin_amdgcn_mfma_f32_16x16x32_bf16(ah[ks], bh, acc[nt], 0, 0, 0);
            acc[nt] = __builtin_amdgcn_mfma_f32_16x16x32_bf16(al[ks], bh, acc[nt], 0, 0, 0);
            acc[nt] = __builtin_amdgcn_mfma_f32_16x16x32_bf16(ah[ks], bl, acc[nt], 0, 0, 0);
        }
    }
    #pragma unroll
    for (int nt = 0; nt < 4; nt++)
        #pragma unroll
        for (int r = 0; r < 4; r++)
            hxb[(m0 + q * 4 + r) * 64 + nt * 16 + ln] = f2bf(acc[nt][r]);
}

// ================= per-node edge aggregation (bf16 table + bf16 hx) ============
__global__ __launch_bounds__(256) void k_edge_agg(const int2* __restrict__ spayload,
                                                  const int* __restrict__ offsets,
                                                  const ushort* __restrict__ hxb,
                                                  const uint* __restrict__ tblb_t,
                                                  float* __restrict__ agg) {
    int wave = threadIdx.x >> 6, lane = threadIdx.x & 63;
    int n = blockIdx.x * 4 + wave;
    if (n >= NA) return;
    int start = offsets[n], end = offsets[n + 1];
    float acc = 0.f;
    for (int base = start; base < end; base += 64) {
        int cnt = min(64, end - base);
        int2 p = (base + lane < end) ? spayload[base + lane] : make_int2(0, 0);
        for (int j = 0; j < cnt; j++) {
            int srcn = __builtin_amdgcn_readlane(p.x, j) & 0x1FFFF;
            float fb = __int_as_float(__builtin_amdgcn_readlane(p.y, j));
            int b = (int)fb;
            float fr = fb - (float)b;
            uint w = tblb_t[(size_t)b * 64 + lane];
            float w0 = __uint_as_float(w << 16);
            float w1 = __uint_as_float(w & 0xffff0000u);
            float wf = fmaf(fr, w1 - w0, w0);
            acc = fmaf(wf, bf2f(hxb[srcn * 64 + lane]), acc);
        }
    }
    agg[n * 64 + lane] = acc;
}

// ================= h += ssp(agg@cf2+b2) @ lin + lb  (fused double MFMA) ========
__global__ __launch_bounds__(256) void k_update(const float* __restrict__ agg,
                                                const ushort* __restrict__ whi,
                                                const ushort* __restrict__ wlo,
                                                int mi_cf2, int mi_lin,
                                                const float* __restrict__ cf2b_t,
                                                const float* __restrict__ linb_t,
                                                float* __restrict__ h) {
    __shared__ ushort Thi[4][16][72];
    __shared__ ushort Tlo[4][16][72];
    int wave = threadIdx.x >> 6, lane = threadIdx.x & 63;
    int tile = blockIdx.x * 4 + wave;
    if (tile >= NTILE) return;
    int m0 = tile * 16;
    int q = lane >> 4, ln = lane & 15;

    // ---- stage 1: T = ssp(agg @ cf2 + b2)
    short8 ah[2], al[2];
    #pragma unroll
    for (int ks = 0; ks < 2; ks++)
        mk_frag(agg + (m0 + ln) * 64 + ks * 32 + q * 8, ah[ks], al[ks]);

    floatx4 acc[4];
    #pragma unroll
    for (int nt = 0; nt < 4; nt++) acc[nt] = (floatx4){0.f, 0.f, 0.f, 0.f};

    const ushort* w2h = whi + mi_cf2 * 4096;
    const ushort* w2l = wlo + mi_cf2 * 4096;
    #pragma unroll
    for (int ks = 0; ks < 2; ks++) {
        #pragma unroll
        for (int nt = 0; nt < 4; nt++) {
            int off = (nt * 16 + ln) * 64 + ks * 32 + q * 8;
            short8 bh = *(const short8*)(w2h + off);
            short8 bl = *(const short8*)(w2l + off);
            acc[nt] = __builtin_amdgcn_mfma_f32_16x16x32_bf16(ah[ks], bh, acc[nt], 0, 0, 0);
            acc[nt] = __builtin_amdgcn_mfma_f32_16x16x32_bf16(al[ks], bh, acc[nt], 0, 0, 0);
            acc[nt] = __builtin_amdgcn_mfma_f32_16x16x32_bf16(ah[ks], bl, acc[nt], 0, 0, 0);
        }
    }
    // epilogue 1: bias + ssp -> per-wave LDS (bf16 hi/lo, A-fragment friendly)
    #pragma unroll
    for (int nt = 0; nt < 4; nt++) {
        float bias = cf2b_t[nt * 16 + ln];
        #pragma unroll
        for (int r = 0; r < 4; r++) {
            float v = ssp(acc[nt][r] + bias);
            ushort hi = f2bf(v);
            Thi[wave][q * 4 + r][nt * 16 + ln] = hi;
            Tlo[wave][q * 4 + r][nt * 16 + ln] = (ushort)f2bf(v - bf2f(hi));
        }
    }
    // same-wave LDS producer/consumer: no barrier needed (per-wave region)

    // ---- stage 2: x = T @ lin ; h += x + lb
    #pragma unroll
    for (int nt = 0; nt < 4; nt++) acc[nt] = (floatx4){0.f, 0.f, 0.f, 0.f};
    const ushort* wlh = whi + mi_lin * 4096;
    const ushort* wll = wlo + mi_lin * 4096;
    #pragma unroll
    for (int ks = 0; ks < 2; ks++) {
        short8 ah2 = *(const short8*)&Thi[wave][ln][ks * 32 + q * 8];
        short8 al2 = *(const short8*)&Tlo[wave][ln][ks * 32 + q * 8];
        #pragma unroll
        for (int nt = 0; nt < 4; nt++) {
            int off = (nt * 16 + ln) * 64 + ks * 32 + q * 8;
            short8 bh = *(const short8*)(wlh + off);
            short8 bl = *(const short8*)(wll + off);
            acc[nt] = __builtin_amdgcn_mfma_f32_16x16x32_bf16(ah2, bh, acc[nt], 0, 0, 0);
            acc[nt] = __builtin_amdgcn_mfma_f32_16x16x32_bf16(al2, bh, acc[nt], 0, 0, 0);
            acc[nt] = __builtin_amdgcn_mfma_f32_16x16x32_bf16(ah2, bl, acc[nt], 0, 0, 0);
        }
    }
    #pragma unroll
    for (int nt = 0; nt < 4; nt++) {
        float bias = linb_t[nt * 16 + ln];
        #pragma unroll
        for (int r = 0; r < 4; r++) {
            int idx = (m0 + q * 4 + r) * 64 + nt * 16 + ln;
            h[idx] += acc[nt][r] + bias;
        }
    }
}

// ================= readout + head =================
__global__ __launch_bounds__(256) void k_readout(const float* __restrict__ h,
                                                 const int* __restrict__ batch,
                                                 float* __restrict__ g) {
    int i = blockIdx.x * 256 + threadIdx.x;
    if (i >= NA * HD) return;
    int n = i >> 6, f = i & 63;
    atomicAdd(&g[batch[n] * HD + f], h[i]);
}

__global__ __launch_bounds__(64) void k_head(const float* __restrict__ g,
                                             const float* __restrict__ o1w,
                                             const float* __restrict__ o1b,
                                             const float* __restrict__ o2w,
                                             const float* __restrict__ o2b,
                                             float* __restrict__ out) {
    int gi = blockIdx.x;
    int lane = threadIdx.x;
    float gv = g[gi * 64 + lane];
    float a = (lane < 32) ? o1b[lane] : 0.f;
    for (int k = 0; k < 64; k++) {
        float w = (lane < 32) ? o1w[k * 32 + lane] : 0.f;
        a = fmaf(__shfl(gv, k), w, a);
    }
    a = fmaxf(a, 0.f);
    float contrib = (lane < 32) ? a * o2w[lane] : 0.f;
    for (int off = 32; off > 0; off >>= 1) contrib += __shfl_down(contrib, off);
    if (lane == 0) out[gi] = contrib + o2b[0];
}

extern "C" void kernel_launch(void* const* d_in, const int* in_sizes, int n_in,
                              void* d_out, int out_size, void* d_ws, size_t ws_size,
                              hipStream_t stream) {
    (void)in_sizes; (void)n_in; (void)out_size; (void)ws_size;
    const int*   z    = (const int*)d_in[0];
    const float* pos  = (const float*)d_in[1];
    const int*   batch= (const int*)d_in[2];
    const int*   ei   = (const int*)d_in[3];
    const float* emb  = (const float*)d_in[4];
    const float* mw1  = (const float*)d_in[5];
    const float* mb1  = (const float*)d_in[6];
    const float* mw2  = (const float*)d_in[7];
    const float* mb2  = (const float*)d_in[8];
    const float* cf1w = (const float*)d_in[9];
    const float* cf2w = (const float*)d_in[10];
    const float* cf2b = (const float*)d_in[11];
    const float* linw = (const float*)d_in[12];
    const float* linb = (const float*)d_in[13];
    const float* o1w  = (const float*)d_in[14];
    const float* o1b  = (const float*)d_in[15];
    const float* o2w  = (const float*)d_in[16];
    const float* o2b  = (const float*)d_in[17];
    float* out = (float*)d_out;

    char* w = (char*)d_ws;
    auto take = [&](size_t bytes) {
        char* p = w;
        w += (bytes + 255) & ~size_t(255);
        return p;
    };
    int*    hist1    = (int*)take(NBKT * 4);
    int*    offsets1 = (int*)take((NBKT + 1) * 4);
    int*    gcursor1 = (int*)take(NBKT * 4);
    int*    offsets  = (int*)take((NA + 1) * 4);
    int2*   brec     = (int2*)take((size_t)NE * 8);
    int2*   spayload = (int2*)take((size_t)NE * 8);
    uint*   tblb     = (uint*)take((size_t)NB * NBINS * HD * 4);
    ushort* whi      = (ushort*)take(9 * 4096 * 2);
    ushort* wlo      = (ushort*)take(9 * 4096 * 2);
    float*  h        = (float*)take((size_t)NA * HD * 4);
    ushort* hxb      = (ushort*)take((size_t)NA * HD * 2);
    float*  agg      = (float*)take((size_t)NA * HD * 4);
    float*  g        = (float*)take((size_t)NGR * HD * 4);

    hipMemsetAsync(hist1, 0, NBKT * 4, stream);
    hipMemsetAsync(g, 0, NGR * HD * 4, stream);

    k_count<<<S1_NB, 1024, 0, stream>>>(ei, hist1);
    k_scan196<<<1, 256, 0, stream>>>(hist1, offsets1, gcursor1, offsets);
    k_sort1<<<S1_NB, 1024, 0, stream>>>(ei, pos, gcursor1, brec);
    k_sort2<<<NBKT, 1024, 0, stream>>>(brec, offsets1, spayload, offsets);
    k_table<<<NB * NBINS, 64, 0, stream>>>(mw1, mb1, mw2, mb2, tblb);
    k_wprep<<<(9 * 4096 + 255) / 256, 256, 0, stream>>>(cf1w, cf2w, linw, whi, wlo);
    k_init_h<<<(NA * HD + 255) / 256, 256, 0, stream>>>(z, emb, h);

    int nodeBlocks = (NA + 3) / 4;
    for (int t = 0; t < NB; t++) {
        k_hx<<<MM_NB, 256, 0, stream>>>(h, whi + (t * 3 + 0) * 4096,
                                        wlo + (t * 3 + 0) * 4096, hxb);
        k_edge_agg<<<nodeBlocks, 256, 0, stream>>>(spayload, offsets, hxb,
                                                   tblb + (size_t)t * NBINS * HD, agg);
        k_update<<<MM_NB, 256, 0, stream>>>(agg, whi, wlo, t * 3 + 1, t * 3 + 2,
                                            cf2b + t * 64, linb + t * 64, h);
    }
    k_readout<<<(NA * HD + 255) / 256, 256, 0, stream>>>(h, batch, g);
    k_head<<<NGR, 64, 0, stream>>>(g, o1w, o1b, o2w, o2b, out);
}

// Round 5
// 476.266 us; speedup vs baseline: 2.5295x; 1.2605x over previous
//
#include <hip/hip_runtime.h>
#include <math.h>

constexpr int NA = 50000;
constexpr int NE = 1600000;
constexpr int NGR = 250;
constexpr int HD = 64;
constexpr int NGAUSS = 50;
constexpr int NB = 3;
constexpr float FCUTOFF = 10.0f;

constexpr int NBINS = 4096;
constexpr float TBL_MAX = 8.6603f;
constexpr float TBL_STEP = TBL_MAX / NBINS;

constexpr int NBKT = (NA + 255) / 256;              // 196
constexpr int S1_EPB = 4096;
constexpr int S1_NB = (NE + S1_EPB - 1) / S1_EPB;   // 391

constexpr int NTILE = NA / 16;                      // 3125 (exact)
constexpr int MM_NB = (NTILE + 3) / 4;              // 782

typedef __attribute__((ext_vector_type(8))) short short8;
typedef __attribute__((ext_vector_type(4))) float floatx4;
typedef unsigned int uint;
typedef unsigned short ushort;

__device__ __forceinline__ float ssp(float v) {
    return fmaxf(v, 0.f) + log1pf(expf(-fabsf(v))) - 0.69314718055994530942f;
}
__device__ __forceinline__ ushort f2bf(float f) {
    uint u = __float_as_uint(f);
    return (ushort)((u + 0x7fffu + ((u >> 16) & 1u)) >> 16);   // RNE
}
__device__ __forceinline__ float bf2f(ushort h) {
    return __uint_as_float(((uint)h) << 16);
}

// ================= sort pipeline =================
__global__ __launch_bounds__(1024) void k_count(const int* __restrict__ ei,
                                                int* __restrict__ hist1) {
    __shared__ int lh[NBKT];
    for (int i = threadIdx.x; i < NBKT; i += 1024) lh[i] = 0;
    __syncthreads();
    int base = blockIdx.x * S1_EPB;
    #pragma unroll
    for (int i = 0; i < 4; i++) {
        int e = base + i * 1024 + threadIdx.x;
        if (e < NE) atomicAdd(&lh[ei[NE + e] >> 8], 1);
    }
    __syncthreads();
    for (int i = threadIdx.x; i < NBKT; i += 1024)
        if (lh[i]) atomicAdd(&hist1[i], lh[i]);
}

__global__ __launch_bounds__(256) void k_scan196(const int* __restrict__ hist1,
                                                 int* __restrict__ offsets1,
                                                 int* __restrict__ gcursor1,
                                                 int* __restrict__ offsets) {
    __shared__ int buf[256];
    int tid = threadIdx.x;
    int v = (tid < NBKT) ? hist1[tid] : 0;
    buf[tid] = v;
    __syncthreads();
    for (int off = 1; off < 256; off <<= 1) {
        int t = (tid >= off) ? buf[tid - off] : 0;
        __syncthreads();
        buf[tid] += t;
        __syncthreads();
    }
    int excl = buf[tid] - v;
    if (tid < NBKT) { offsets1[tid] = excl; gcursor1[tid] = excl; }
    if (tid == NBKT - 1) offsets1[NBKT] = excl + v;
    if (tid == 0) offsets[NA] = NE;
}

__global__ __launch_bounds__(1024) void k_sort1(const int* __restrict__ ei,
                                                const float* __restrict__ pos,
                                                int* __restrict__ gcursor1,
                                                int2* __restrict__ brec) {
    __shared__ int2 recs[S1_EPB];
    __shared__ unsigned char rbkt[S1_EPB];
    __shared__ int hist[NBKT];
    __shared__ int lcur[NBKT];
    __shared__ int delta[NBKT];
    __shared__ int scanbuf[256];
    int tid = threadIdx.x;
    for (int i = tid; i < NBKT; i += 1024) hist[i] = 0;
    __syncthreads();
    int2 myrec[4];
    int mybkt[4];
    int base = blockIdx.x * S1_EPB;
    #pragma unroll
    for (int i = 0; i < 4; i++) {
        int e = base + i * 1024 + tid;
        mybkt[i] = -1;
        if (e < NE) {
            int s = ei[e];
            int dt = ei[NE + e];
            float dx = pos[dt * 3 + 0] - pos[s * 3 + 0];
            float dy = pos[dt * 3 + 1] - pos[s * 3 + 1];
            float dz = pos[dt * 3 + 2] - pos[s * 3 + 2];
            float d = sqrtf(dx * dx + dy * dy + dz * dz);
            float fb = fminf(d * (1.0f / TBL_STEP), (float)NBINS - 1e-3f);
            myrec[i] = make_int2(s | ((dt & 255) << 17), __float_as_int(fb));
            mybkt[i] = dt >> 8;
            atomicAdd(&hist[mybkt[i]], 1);
        }
    }
    __syncthreads();
    int v = (tid < NBKT) ? hist[tid] : 0;
    if (tid < 256) scanbuf[tid] = v;
    __syncthreads();
    for (int off = 1; off < 256; off <<= 1) {
        int t = (tid >= off && tid < 256) ? scanbuf[tid - off] : 0;
        __syncthreads();
        if (tid < 256) scanbuf[tid] += t;
        __syncthreads();
    }
    if (tid < NBKT) {
        int excl = scanbuf[tid] - v;
        lcur[tid] = excl;
        int gbase = atomicAdd(&gcursor1[tid], v);
        delta[tid] = gbase - excl;
    }
    __syncthreads();
    #pragma unroll
    for (int i = 0; i < 4; i++) {
        if (mybkt[i] >= 0) {
            int r = atomicAdd(&lcur[mybkt[i]], 1);
            recs[r] = myrec[i];
            rbkt[r] = (unsigned char)mybkt[i];
        }
    }
    __syncthreads();
    int total = min(S1_EPB, NE - base);
    for (int p = tid; p < total; p += 1024)
        brec[delta[rbkt[p]] + p] = recs[p];
}

__global__ __launch_bounds__(1024) void k_sort2(const int2* __restrict__ brec,
                                                const int* __restrict__ offsets1,
                                                int2* __restrict__ spayload,
                                                int* __restrict__ offsets) {
    __shared__ int cnt[256];
    __shared__ int lstart[256];
    __shared__ int lcur[256];
    int b = blockIdx.x;
    int tid = threadIdx.x;
    if (tid < 256) cnt[tid] = 0;
    __syncthreads();
    int rbase = offsets1[b], rend = offsets1[b + 1];
    for (int p = rbase + tid; p < rend; p += 1024)
        atomicAdd(&cnt[(brec[p].x >> 17) & 255], 1);
    __syncthreads();
    int v = (tid < 256) ? cnt[tid] : 0;
    if (tid < 256) lstart[tid] = v;
    __syncthreads();
    for (int off = 1; off < 256; off <<= 1) {
        int t = (tid >= off && tid < 256) ? lstart[tid - off] : 0;
        __syncthreads();
        if (tid < 256) lstart[tid] += t;
        __syncthreads();
    }
    if (tid < 256) {
        lstart[tid] -= v;
        lcur[tid] = rbase + lstart[tid];
        int node = (b << 8) + tid;
        if (node < NA) offsets[node] = rbase + lstart[tid];
    }
    __syncthreads();
    for (int p = rbase + tid; p < rend; p += 1024) {
        int2 r = brec[p];
        int slot = atomicAdd(&lcur[(r.x >> 17) & 255], 1);
        spayload[slot] = r;
    }
}

// ================= Wf table, packed bf16 pair per (bin, channel) =================
__global__ __launch_bounds__(64) void k_table(const float* __restrict__ w1,
                                              const float* __restrict__ b1,
                                              const float* __restrict__ w2,
                                              const float* __restrict__ b2,
                                              uint* __restrict__ tblb) {
    int blk = blockIdx.x;
    int t = blk / NBINS;
    int bin = blk % NBINS;
    int f = threadIdx.x;
    __shared__ float rbf0[NGAUSS], rbf1[NGAUSS];
    __shared__ float act0[HD], act1[HD];
    float d0 = bin * TBL_STEP;
    float d1 = (bin + 1) * TBL_STEP;
    if (f < NGAUSS) {
        float spacing = FCUTOFF / (NGAUSS - 1);
        float off = f * spacing;
        float coeff = -0.5f / (spacing * spacing);
        float u0 = d0 - off, u1 = d1 - off;
        rbf0[f] = expf(coeff * u0 * u0);
        rbf1[f] = expf(coeff * u1 * u1);
    }
    __syncthreads();
    const float* W1 = w1 + t * NGAUSS * HD;
    float a0 = b1[t * HD + f], a1 = a0;
    for (int g = 0; g < NGAUSS; g++) {
        float w = W1[g * HD + f];
        a0 = fmaf(rbf0[g], w, a0);
        a1 = fmaf(rbf1[g], w, a1);
    }
    act0[f] = ssp(a0);
    act1[f] = ssp(a1);
    __syncthreads();
    const float* W2 = w2 + t * HD * HD;
    float o0 = b2[t * HD + f], o1 = o0;
    for (int j = 0; j < HD; j++) {
        float w = W2[j * HD + f];
        o0 = fmaf(act0[j], w, o0);
        o1 = fmaf(act1[j], w, o1);
    }
    float C0 = 0.5f * (cosf(d0 * (float)M_PI / FCUTOFF) + 1.0f);
    float C1 = 0.5f * (cosf(d1 * (float)M_PI / FCUTOFF) + 1.0f);
    tblb[(size_t)(t * NBINS + bin) * HD + f] =
        ((uint)f2bf(o1 * C1) << 16) | (uint)f2bf(o0 * C0);
}

// ================= weight prep: bf16 hi/lo in B-fragment order [mat][n][k] =====
__global__ __launch_bounds__(256) void k_wprep(const float* __restrict__ cf1w,
                                               const float* __restrict__ cf2w,
                                               const float* __restrict__ linw,
                                               ushort* __restrict__ whi,
                                               ushort* __restrict__ wlo) {
    int idx = blockIdx.x * 256 + threadIdx.x;
    if (idx >= 9 * 4096) return;
    int mi = idx >> 12;
    int t = mi / 3, which = mi % 3;
    int rem = idx & 4095;
    int n = rem >> 6, k = rem & 63;
    const float* src = (which == 0) ? cf1w : (which == 1) ? cf2w : linw;
    float v = src[t * 4096 + k * 64 + n];
    ushort hi = f2bf(v);
    ushort lo = f2bf(v - bf2f(hi));
    whi[mi * 4096 + n * 64 + k] = hi;
    wlo[mi * 4096 + n * 64 + k] = lo;
}

// ================= h init =================
__global__ __launch_bounds__(256) void k_init_h(const int* __restrict__ z,
                                                const float* __restrict__ emb,
                                                float* __restrict__ h) {
    int i = blockIdx.x * 256 + threadIdx.x;
    if (i >= NA * HD) return;
    int n = i >> 6, f = i & 63;
    h[i] = emb[z[n] * HD + f];
}

__device__ __forceinline__ void mk_frag(const float* p, short8& hi, short8& lo) {
    float4 a0 = *(const float4*)p;
    float4 a1 = *(const float4*)(p + 4);
    float av[8] = {a0.x, a0.y, a0.z, a0.w, a1.x, a1.y, a1.z, a1.w};
    #pragma unroll
    for (int j = 0; j < 8; j++) {
        ushort h = f2bf(av[j]);
        hi[j] = (short)h;
        lo[j] = (short)f2bf(av[j] - bf2f(h));
    }
}

// ================= hx = h @ cf1  (t=0 only; later fused into k_update) =========
__global__ __launch_bounds__(256) void k_hx(const float* __restrict__ h,
                                            const ushort* __restrict__ whi_m,
                                            const ushort* __restrict__ wlo_m,
                                            ushort* __restrict__ hxb) {
    int wave = threadIdx.x >> 6, lane = threadIdx.x & 63;
    int tile = blockIdx.x * 4 + wave;
    if (tile >= NTILE) return;
    int m0 = tile * 16;
    int q = lane >> 4, ln = lane & 15;

    short8 ah[2], al[2];
    #pragma unroll
    for (int ks = 0; ks < 2; ks++)
        mk_frag(h + (m0 + ln) * 64 + ks * 32 + q * 8, ah[ks], al[ks]);

    floatx4 acc[4];
    #pragma unroll
    for (int nt = 0; nt < 4; nt++) acc[nt] = (floatx4){0.f, 0.f, 0.f, 0.f};

    #pragma unroll
    for (int ks = 0; ks < 2; ks++) {
        #pragma unroll
        for (int nt = 0; nt < 4; nt++) {
            int off = (nt * 16 + ln) * 64 + ks * 32 + q * 8;
            short8 bh = *(const short8*)(whi_m + off);
            short8 bl = *(const short8*)(wlo_m + off);
            acc[nt] = __builtin_amdgcn_mfma_f32_16x16x32_bf16(ah[ks], bh, acc[nt], 0, 0, 0);
            acc[nt] = __builtin_amdgcn_mfma_f32_16x16x32_bf16(al[ks], bh, acc[nt], 0, 0, 0);
            acc[nt] = __builtin_amdgcn_mfma_f32_16x16x32_bf16(ah[ks], bl, acc[nt], 0, 0, 0);
        }
    }
    #pragma unroll
    for (int nt = 0; nt < 4; nt++)
        #pragma unroll
        for (int r = 0; r < 4; r++)
            hxb[(m0 + q * 4 + r) * 64 + nt * 16 + ln] = f2bf(acc[nt][r]);
}

// ================= per-node edge aggregation: 4 edges/iteration ================
// lane = e4*16 + c16; lane handles edge (base+e4), channels c16*4..+3
__global__ __launch_bounds__(256) void k_edge_agg(const int2* __restrict__ spayload,
                                                  const int* __restrict__ offsets,
                                                  const ushort* __restrict__ hxb,
                                                  const uint* __restrict__ tblb_t,
                                                  float* __restrict__ agg) {
    int wave = threadIdx.x >> 6, lane = threadIdx.x & 63;
    int n = blockIdx.x * 4 + wave;
    if (n >= NA) return;
    int e4 = lane >> 4, c16 = lane & 15;
    int start = offsets[n], end = offsets[n + 1];
    float a0 = 0.f, a1 = 0.f, a2 = 0.f, a3 = 0.f;
    for (int base = start; base < end; base += 4) {
        int e = base + e4;
        bool valid = e < end;
        int ec = valid ? e : (end - 1);
        int2 p = spayload[ec];
        int srcn = p.x & 0x1FFFF;
        float fb = __int_as_float(p.y);
        int b = (int)fb;
        float fr = fb - (float)b;
        uint4 w = *(const uint4*)(tblb_t + ((size_t)b << 6) + (c16 << 2));
        uint2 hv = *(const uint2*)(hxb + ((size_t)srcn << 6) + (c16 << 2));
        if (!valid) { hv.x = 0u; hv.y = 0u; }
        float h0 = __uint_as_float(hv.x << 16);
        float h1 = __uint_as_float(hv.x & 0xffff0000u);
        float h2 = __uint_as_float(hv.y << 16);
        float h3 = __uint_as_float(hv.y & 0xffff0000u);
        float w0l = __uint_as_float(w.x << 16), w0h = __uint_as_float(w.x & 0xffff0000u);
        float w1l = __uint_as_float(w.y << 16), w1h = __uint_as_float(w.y & 0xffff0000u);
        float w2l = __uint_as_float(w.z << 16), w2h = __uint_as_float(w.z & 0xffff0000u);
        float w3l = __uint_as_float(w.w << 16), w3h = __uint_as_float(w.w & 0xffff0000u);
        a0 = fmaf(fmaf(fr, w0h - w0l, w0l), h0, a0);
        a1 = fmaf(fmaf(fr, w1h - w1l, w1l), h1, a1);
        a2 = fmaf(fmaf(fr, w2h - w2l, w2l), h2, a2);
        a3 = fmaf(fmaf(fr, w3h - w3l, w3l), h3, a3);
    }
    a0 += __shfl_xor(a0, 16); a0 += __shfl_xor(a0, 32);
    a1 += __shfl_xor(a1, 16); a1 += __shfl_xor(a1, 32);
    a2 += __shfl_xor(a2, 16); a2 += __shfl_xor(a2, 32);
    a3 += __shfl_xor(a3, 16); a3 += __shfl_xor(a3, 32);
    if (e4 == 0)
        *(float4*)(agg + ((size_t)n << 6) + (c16 << 2)) = make_float4(a0, a1, a2, a3);
}

// ================= h += ssp(agg@cf2+b2)@lin + lb ; fused next-layer hx =========
__global__ __launch_bounds__(256) void k_update(const float* __restrict__ agg,
                                                const ushort* __restrict__ whi,
                                                const ushort* __restrict__ wlo,
                                                int mi_cf2, int mi_lin, int mi_next,
                                                const float* __restrict__ cf2b_t,
                                                const float* __restrict__ linb_t,
                                                float* __restrict__ h,
                                                ushort* __restrict__ hxb) {
    __shared__ ushort Thi[4][16][72];
    __shared__ ushort Tlo[4][16][72];
    __shared__ __align__(16) float Hst[4][16][68];
    int wave = threadIdx.x >> 6, lane = threadIdx.x & 63;
    int tile = blockIdx.x * 4 + wave;
    if (tile >= NTILE) return;
    int m0 = tile * 16;
    int q = lane >> 4, ln = lane & 15;

    // ---- stage 1: T = ssp(agg @ cf2 + b2)
    short8 ah[2], al[2];
    #pragma unroll
    for (int ks = 0; ks < 2; ks++)
        mk_frag(agg + (m0 + ln) * 64 + ks * 32 + q * 8, ah[ks], al[ks]);

    floatx4 acc[4];
    #pragma unroll
    for (int nt = 0; nt < 4; nt++) acc[nt] = (floatx4){0.f, 0.f, 0.f, 0.f};

    const ushort* w2h = whi + mi_cf2 * 4096;
    const ushort* w2l = wlo + mi_cf2 * 4096;
    #pragma unroll
    for (int ks = 0; ks < 2; ks++) {
        #pragma unroll
        for (int nt = 0; nt < 4; nt++) {
            int off = (nt * 16 + ln) * 64 + ks * 32 + q * 8;
            short8 bh = *(const short8*)(w2h + off);
            short8 bl = *(const short8*)(w2l + off);
            acc[nt] = __builtin_amdgcn_mfma_f32_16x16x32_bf16(ah[ks], bh, acc[nt], 0, 0, 0);
            acc[nt] = __builtin_amdgcn_mfma_f32_16x16x32_bf16(al[ks], bh, acc[nt], 0, 0, 0);
            acc[nt] = __builtin_amdgcn_mfma_f32_16x16x32_bf16(ah[ks], bl, acc[nt], 0, 0, 0);
        }
    }
    #pragma unroll
    for (int nt = 0; nt < 4; nt++) {
        float bias = cf2b_t[nt * 16 + ln];
        #pragma unroll
        for (int r = 0; r < 4; r++) {
            float v = ssp(acc[nt][r] + bias);
            ushort hi = f2bf(v);
            Thi[wave][q * 4 + r][nt * 16 + ln] = hi;
            Tlo[wave][q * 4 + r][nt * 16 + ln] = (ushort)f2bf(v - bf2f(hi));
        }
    }
    // same-wave LDS producer/consumer: no barrier needed (per-wave region)

    // ---- stage 2: x = T @ lin ; hnew = h + x + lb
    #pragma unroll
    for (int nt = 0; nt < 4; nt++) acc[nt] = (floatx4){0.f, 0.f, 0.f, 0.f};
    const ushort* wlh = whi + mi_lin * 4096;
    const ushort* wll = wlo + mi_lin * 4096;
    #pragma unroll
    for (int ks = 0; ks < 2; ks++) {
        short8 ah2 = *(const short8*)&Thi[wave][ln][ks * 32 + q * 8];
        short8 al2 = *(const short8*)&Tlo[wave][ln][ks * 32 + q * 8];
        #pragma unroll
        for (int nt = 0; nt < 4; nt++) {
            int off = (nt * 16 + ln) * 64 + ks * 32 + q * 8;
            short8 bh = *(const short8*)(wlh + off);
            short8 bl = *(const short8*)(wll + off);
            acc[nt] = __builtin_amdgcn_mfma_f32_16x16x32_bf16(ah2, bh, acc[nt], 0, 0, 0);
            acc[nt] = __builtin_amdgcn_mfma_f32_16x16x32_bf16(al2, bh, acc[nt], 0, 0, 0);
            acc[nt] = __builtin_amdgcn_mfma_f32_16x16x32_bf16(ah2, bl, acc[nt], 0, 0, 0);
        }
    }
    #pragma unroll
    for (int nt = 0; nt < 4; nt++) {
        float bias = linb_t[nt * 16 + ln];
        #pragma unroll
        for (int r = 0; r < 4; r++) {
            int idx = (m0 + q * 4 + r) * 64 + nt * 16 + ln;
            float hn = h[idx] + acc[nt][r] + bias;
            h[idx] = hn;
            Hst[wave][q * 4 + r][nt * 16 + ln] = hn;
        }
    }

    // ---- stage 3 (fused next-layer hx): hxb = bf16(Hst @ cf1_next)
    if (mi_next >= 0) {
        short8 ah3[2], al3[2];
        #pragma unroll
        for (int ks = 0; ks < 2; ks++)
            mk_frag(&Hst[wave][ln][ks * 32 + q * 8], ah3[ks], al3[ks]);
        #pragma unroll
        for (int nt = 0; nt < 4; nt++) acc[nt] = (floatx4){0.f, 0.f, 0.f, 0.f};
        const ushort* wnh = whi + mi_next * 4096;
        const ushort* wnl = wlo + mi_next * 4096;
        #pragma unroll
        for (int ks = 0; ks < 2; ks++) {
            #pragma unroll
            for (int nt = 0; nt < 4; nt++) {
                int off = (nt * 16 + ln) * 64 + ks * 32 + q * 8;
                short8 bh = *(const short8*)(wnh + off);
                short8 bl = *(const short8*)(wnl + off);
                acc[nt] = __builtin_amdgcn_mfma_f32_16x16x32_bf16(ah3[ks], bh, acc[nt], 0, 0, 0);
                acc[nt] = __builtin_amdgcn_mfma_f32_16x16x32_bf16(al3[ks], bh, acc[nt], 0, 0, 0);
                acc[nt] = __builtin_amdgcn_mfma_f32_16x16x32_bf16(ah3[ks], bl, acc[nt], 0, 0, 0);
            }
        }
        #pragma unroll
        for (int nt = 0; nt < 4; nt++)
            #pragma unroll
            for (int r = 0; r < 4; r++)
                hxb[(m0 + q * 4 + r) * 64 + nt * 16 + ln] = f2bf(acc[nt][r]);
    }
}

// ================= readout + head =================
__global__ __launch_bounds__(256) void k_readout(const float* __restrict__ h,
                                                 const int* __restrict__ batch,
                                                 float* __restrict__ g) {
    int i = blockIdx.x * 256 + threadIdx.x;
    if (i >= NA * HD) return;
    int n = i >> 6, f = i & 63;
    atomicAdd(&g[batch[n] * HD + f], h[i]);
}

__global__ __launch_bounds__(64) void k_head(const float* __restrict__ g,
                                             const float* __restrict__ o1w,
                                             const float* __restrict__ o1b,
                                             const float* __restrict__ o2w,
                                             const float* __restrict__ o2b,
                                             float* __restrict__ out) {
    int gi = blockIdx.x;
    int lane = threadIdx.x;
    float gv = g[gi * 64 + lane];
    float a = (lane < 32) ? o1b[lane] : 0.f;
    for (int k = 0; k < 64; k++) {
        float w = (lane < 32) ? o1w[k * 32 + lane] : 0.f;
        a = fmaf(__shfl(gv, k), w, a);
    }
    a = fmaxf(a, 0.f);
    float contrib = (lane < 32) ? a * o2w[lane] : 0.f;
    for (int off = 32; off > 0; off >>= 1) contrib += __shfl_down(contrib, off);
    if (lane == 0) out[gi] = contrib + o2b[0];
}

extern "C" void kernel_launch(void* const* d_in, const int* in_sizes, int n_in,
                              void* d_out, int out_size, void* d_ws, size_t ws_size,
                              hipStream_t stream) {
    (void)in_sizes; (void)n_in; (void)out_size; (void)ws_size;
    const int*   z    = (const int*)d_in[0];
    const float* pos  = (const float*)d_in[1];
    const int*   batch= (const int*)d_in[2];
    const int*   ei   = (const int*)d_in[3];
    const float* emb  = (const float*)d_in[4];
    const float* mw1  = (const float*)d_in[5];
    const float* mb1  = (const float*)d_in[6];
    const float* mw2  = (const float*)d_in[7];
    const float* mb2  = (const float*)d_in[8];
    const float* cf1w = (const float*)d_in[9];
    const float* cf2w = (const float*)d_in[10];
    const float* cf2b = (const float*)d_in[11];
    const float* linw = (const float*)d_in[12];
    const float* linb = (const float*)d_in[13];
    const float* o1w  = (const float*)d_in[14];
    const float* o1b  = (const float*)d_in[15];
    const float* o2w  = (const float*)d_in[16];
    const float* o2b  = (const float*)d_in[17];
    float* out = (float*)d_out;

    char* w = (char*)d_ws;
    auto take = [&](size_t bytes) {
        char* p = w;
        w += (bytes + 255) & ~size_t(255);
        return p;
    };
    int*    hist1    = (int*)take(NBKT * 4);
    int*    offsets1 = (int*)take((NBKT + 1) * 4);
    int*    gcursor1 = (int*)take(NBKT * 4);
    int*    offsets  = (int*)take((NA + 1) * 4);
    int2*   brec     = (int2*)take((size_t)NE * 8);
    int2*   spayload = (int2*)take((size_t)NE * 8);
    uint*   tblb     = (uint*)take((size_t)NB * NBINS * HD * 4);
    ushort* whi      = (ushort*)take(9 * 4096 * 2);
    ushort* wlo      = (ushort*)take(9 * 4096 * 2);
    float*  h        = (float*)take((size_t)NA * HD * 4);
    ushort* hxb      = (ushort*)take((size_t)NA * HD * 2);
    float*  agg      = (float*)take((size_t)NA * HD * 4);
    float*  g        = (float*)take((size_t)NGR * HD * 4);

    hipMemsetAsync(hist1, 0, NBKT * 4, stream);
    hipMemsetAsync(g, 0, NGR * HD * 4, stream);

    k_count<<<S1_NB, 1024, 0, stream>>>(ei, hist1);
    k_scan196<<<1, 256, 0, stream>>>(hist1, offsets1, gcursor1, offsets);
    k_sort1<<<S1_NB, 1024, 0, stream>>>(ei, pos, gcursor1, brec);
    k_sort2<<<NBKT, 1024, 0, stream>>>(brec, offsets1, spayload, offsets);
    k_table<<<NB * NBINS, 64, 0, stream>>>(mw1, mb1, mw2, mb2, tblb);
    k_wprep<<<(9 * 4096 + 255) / 256, 256, 0, stream>>>(cf1w, cf2w, linw, whi, wlo);
    k_init_h<<<(NA * HD + 255) / 256, 256, 0, stream>>>(z, emb, h);

    int nodeBlocks = (NA + 3) / 4;
    k_hx<<<MM_NB, 256, 0, stream>>>(h, whi, wlo, hxb);   // t=0 cf1 is mat index 0
    for (int t = 0; t < NB; t++) {
        k_edge_agg<<<nodeBlocks, 256, 0, stream>>>(spayload, offsets, hxb,
                                                   tblb + (size_t)t * NBINS * HD, agg);
        int mi_next = (t < NB - 1) ? ((t + 1) * 3 + 0) : -1;
        k_update<<<MM_NB, 256, 0, stream>>>(agg, whi, wlo, t * 3 + 1, t * 3 + 2, mi_next,
                                            cf2b + t * 64, linb + t * 64, h, hxb);
    }
    k_readout<<<(NA * HD + 255) / 256, 256, 0, stream>>>(h, batch, g);
    k_head<<<NGR, 64, 0, stream>>>(g, o1w, o1b, o2w, o2b, out);
}

// Round 6
// 421.074 us; speedup vs baseline: 2.8611x; 1.1311x over previous
//
#include <hip/hip_runtime.h>
#include <math.h>

constexpr int NA = 50000;
constexpr int NE = 1600000;
constexpr int NGR = 250;
constexpr int HD = 64;
constexpr int NGAUSS = 50;
constexpr int NB = 3;
constexpr float FCUTOFF = 10.0f;

constexpr int NBINS = 16384;                        // nearest-bin table
constexpr float TBL_MAX = 8.6603f;                  // > 5*sqrt(3)
constexpr float TBL_STEP = TBL_MAX / NBINS;

constexpr int NBKT = (NA + 255) / 256;              // 196
constexpr int S1_EPB = 4096;
constexpr int S1_NB = (NE + S1_EPB - 1) / S1_EPB;   // 391

constexpr int NTILE = NA / 16;                      // 3125 (exact)
constexpr int MM_NB = (NTILE + 3) / 4;              // 782

typedef __attribute__((ext_vector_type(8))) short short8;
typedef __attribute__((ext_vector_type(4))) float floatx4;
typedef unsigned int uint;
typedef unsigned short ushort;

__device__ __forceinline__ float ssp(float v) {
    return fmaxf(v, 0.f) + log1pf(expf(-fabsf(v))) - 0.69314718055994530942f;
}
__device__ __forceinline__ ushort f2bf(float f) {
    uint u = __float_as_uint(f);
    return (ushort)((u + 0x7fffu + ((u >> 16) & 1u)) >> 16);   // RNE
}
__device__ __forceinline__ float bf2f(ushort h) {
    return __uint_as_float(((uint)h) << 16);
}

// ================= sort pipeline =================
__global__ __launch_bounds__(1024) void k_count(const int* __restrict__ ei,
                                                int* __restrict__ hist1) {
    __shared__ int lh[NBKT];
    for (int i = threadIdx.x; i < NBKT; i += 1024) lh[i] = 0;
    __syncthreads();
    int base = blockIdx.x * S1_EPB;
    #pragma unroll
    for (int i = 0; i < 4; i++) {
        int e = base + i * 1024 + threadIdx.x;
        if (e < NE) atomicAdd(&lh[ei[NE + e] >> 8], 1);
    }
    __syncthreads();
    for (int i = threadIdx.x; i < NBKT; i += 1024)
        if (lh[i]) atomicAdd(&hist1[i], lh[i]);
}

__global__ __launch_bounds__(256) void k_scan196(const int* __restrict__ hist1,
                                                 int* __restrict__ offsets1,
                                                 int* __restrict__ gcursor1,
                                                 int* __restrict__ offsets) {
    __shared__ int buf[256];
    int tid = threadIdx.x;
    int v = (tid < NBKT) ? hist1[tid] : 0;
    buf[tid] = v;
    __syncthreads();
    for (int off = 1; off < 256; off <<= 1) {
        int t = (tid >= off) ? buf[tid - off] : 0;
        __syncthreads();
        buf[tid] += t;
        __syncthreads();
    }
    int excl = buf[tid] - v;
    if (tid < NBKT) { offsets1[tid] = excl; gcursor1[tid] = excl; }
    if (tid == NBKT - 1) offsets1[NBKT] = excl + v;
    if (tid == 0) offsets[NA] = NE;
}

__global__ __launch_bounds__(1024) void k_sort1(const int* __restrict__ ei,
                                                const float* __restrict__ pos,
                                                int* __restrict__ gcursor1,
                                                int2* __restrict__ brec) {
    __shared__ int2 recs[S1_EPB];
    __shared__ unsigned char rbkt[S1_EPB];
    __shared__ int hist[NBKT];
    __shared__ int lcur[NBKT];
    __shared__ int delta[NBKT];
    __shared__ int scanbuf[256];
    int tid = threadIdx.x;
    for (int i = tid; i < NBKT; i += 1024) hist[i] = 0;
    __syncthreads();
    int2 myrec[4];
    int mybkt[4];
    int base = blockIdx.x * S1_EPB;
    #pragma unroll
    for (int i = 0; i < 4; i++) {
        int e = base + i * 1024 + tid;
        mybkt[i] = -1;
        if (e < NE) {
            int s = ei[e];
            int dt = ei[NE + e];
            float dx = pos[dt * 3 + 0] - pos[s * 3 + 0];
            float dy = pos[dt * 3 + 1] - pos[s * 3 + 1];
            float dz = pos[dt * 3 + 2] - pos[s * 3 + 2];
            float d = sqrtf(dx * dx + dy * dy + dz * dz);
            int bin = (int)(d * (1.0f / TBL_STEP) + 0.5f);
            bin = min(bin, NBINS - 1);
            myrec[i] = make_int2(s | ((dt & 255) << 17), bin);
            mybkt[i] = dt >> 8;
            atomicAdd(&hist[mybkt[i]], 1);
        }
    }
    __syncthreads();
    int v = (tid < NBKT) ? hist[tid] : 0;
    if (tid < 256) scanbuf[tid] = v;
    __syncthreads();
    for (int off = 1; off < 256; off <<= 1) {
        int t = (tid >= off && tid < 256) ? scanbuf[tid - off] : 0;
        __syncthreads();
        if (tid < 256) scanbuf[tid] += t;
        __syncthreads();
    }
    if (tid < NBKT) {
        int excl = scanbuf[tid] - v;
        lcur[tid] = excl;
        int gbase = atomicAdd(&gcursor1[tid], v);
        delta[tid] = gbase - excl;
    }
    __syncthreads();
    #pragma unroll
    for (int i = 0; i < 4; i++) {
        if (mybkt[i] >= 0) {
            int r = atomicAdd(&lcur[mybkt[i]], 1);
            recs[r] = myrec[i];
            rbkt[r] = (unsigned char)mybkt[i];
        }
    }
    __syncthreads();
    int total = min(S1_EPB, NE - base);
    for (int p = tid; p < total; p += 1024)
        brec[delta[rbkt[p]] + p] = recs[p];
}

__global__ __launch_bounds__(1024) void k_sort2(const int2* __restrict__ brec,
                                                const int* __restrict__ offsets1,
                                                int2* __restrict__ spayload,
                                                int* __restrict__ offsets) {
    __shared__ int cnt[256];
    __shared__ int lstart[256];
    __shared__ int lcur[256];
    int b = blockIdx.x;
    int tid = threadIdx.x;
    if (tid < 256) cnt[tid] = 0;
    __syncthreads();
    int rbase = offsets1[b], rend = offsets1[b + 1];
    for (int p = rbase + tid; p < rend; p += 1024)
        atomicAdd(&cnt[(brec[p].x >> 17) & 255], 1);
    __syncthreads();
    int v = (tid < 256) ? cnt[tid] : 0;
    if (tid < 256) lstart[tid] = v;
    __syncthreads();
    for (int off = 1; off < 256; off <<= 1) {
        int t = (tid >= off && tid < 256) ? lstart[tid - off] : 0;
        __syncthreads();
        if (tid < 256) lstart[tid] += t;
        __syncthreads();
    }
    if (tid < 256) {
        lstart[tid] -= v;
        lcur[tid] = rbase + lstart[tid];
        int node = (b << 8) + tid;
        if (node < NA) offsets[node] = rbase + lstart[tid];
    }
    __syncthreads();
    for (int p = rbase + tid; p < rend; p += 1024) {
        int2 r = brec[p];
        int slot = atomicAdd(&lcur[(r.x >> 17) & 255], 1);
        spayload[slot] = r;
    }
}

// ================= Wf table: nearest-bin, plain bf16 [t][bin][64] =================
__global__ __launch_bounds__(64) void k_table(const float* __restrict__ w1,
                                              const float* __restrict__ b1,
                                              const float* __restrict__ w2,
                                              const float* __restrict__ b2,
                                              ushort* __restrict__ tblb) {
    int blk = blockIdx.x;                // t*NBINS + bin
    int t = blk / NBINS;
    int bin = blk % NBINS;
    int f = threadIdx.x;
    __shared__ float rbf[NGAUSS];
    __shared__ float act[HD];
    float d = bin * TBL_STEP;
    if (f < NGAUSS) {
        float spacing = FCUTOFF / (NGAUSS - 1);
        float off = f * spacing;
        float coeff = -0.5f / (spacing * spacing);
        float u = d - off;
        rbf[f] = expf(coeff * u * u);
    }
    __syncthreads();
    const float* W1 = w1 + t * NGAUSS * HD;
    float a = b1[t * HD + f];
    for (int g = 0; g < NGAUSS; g++) a = fmaf(rbf[g], W1[g * HD + f], a);
    act[f] = ssp(a);
    __syncthreads();
    const float* W2 = w2 + t * HD * HD;
    float o = b2[t * HD + f];
    for (int j = 0; j < HD; j++) o = fmaf(act[j], W2[j * HD + f], o);
    float C = 0.5f * (cosf(d * (float)M_PI / FCUTOFF) + 1.0f);
    tblb[(size_t)blk * HD + f] = f2bf(o * C);
}

// ================= weight prep: bf16 hi/lo in B-fragment order [mat][n][k] =====
__global__ __launch_bounds__(256) void k_wprep(const float* __restrict__ cf1w,
                                               const float* __restrict__ cf2w,
                                               const float* __restrict__ linw,
                                               ushort* __restrict__ whi,
                                               ushort* __restrict__ wlo) {
    int idx = blockIdx.x * 256 + threadIdx.x;
    if (idx >= 9 * 4096) return;
    int mi = idx >> 12;
    int t = mi / 3, which = mi % 3;
    int rem = idx & 4095;
    int n = rem >> 6, k = rem & 63;
    const float* src = (which == 0) ? cf1w : (which == 1) ? cf2w : linw;
    float v = src[t * 4096 + k * 64 + n];
    ushort hi = f2bf(v);
    ushort lo = f2bf(v - bf2f(hi));
    whi[mi * 4096 + n * 64 + k] = hi;
    wlo[mi * 4096 + n * 64 + k] = lo;
}

__device__ __forceinline__ void mk_frag2(float4 a0, float4 a1, short8& hi, short8& lo) {
    float av[8] = {a0.x, a0.y, a0.z, a0.w, a1.x, a1.y, a1.z, a1.w};
    #pragma unroll
    for (int j = 0; j < 8; j++) {
        ushort h = f2bf(av[j]);
        hi[j] = (short)h;
        lo[j] = (short)f2bf(av[j] - bf2f(h));
    }
}
__device__ __forceinline__ void mk_frag(const float* p, short8& hi, short8& lo) {
    mk_frag2(*(const float4*)p, *(const float4*)(p + 4), hi, lo);
}

// ================= fused h-init + first hx: h = emb[z]; hxb = bf16(h @ cf1_0) ===
__global__ __launch_bounds__(256) void k_hx0(const int* __restrict__ z,
                                             const float* __restrict__ emb,
                                             const ushort* __restrict__ whi_m,
                                             const ushort* __restrict__ wlo_m,
                                             float* __restrict__ h,
                                             ushort* __restrict__ hxb) {
    int wave = threadIdx.x >> 6, lane = threadIdx.x & 63;
    int tile = blockIdx.x * 4 + wave;
    if (tile >= NTILE) return;
    int m0 = tile * 16;
    int q = lane >> 4, ln = lane & 15;
    int row = m0 + ln;
    int zr = z[row];

    short8 ah[2], al[2];
    #pragma unroll
    for (int ks = 0; ks < 2; ks++) {
        float4 a0 = *(const float4*)(emb + zr * 64 + ks * 32 + q * 8);
        float4 a1 = *(const float4*)(emb + zr * 64 + ks * 32 + q * 8 + 4);
        *(float4*)(h + (size_t)row * 64 + ks * 32 + q * 8) = a0;
        *(float4*)(h + (size_t)row * 64 + ks * 32 + q * 8 + 4) = a1;
        mk_frag2(a0, a1, ah[ks], al[ks]);
    }
    floatx4 acc[4];
    #pragma unroll
    for (int nt = 0; nt < 4; nt++) acc[nt] = (floatx4){0.f, 0.f, 0.f, 0.f};
    #pragma unroll
    for (int ks = 0; ks < 2; ks++) {
        #pragma unroll
        for (int nt = 0; nt < 4; nt++) {
            int off = (nt * 16 + ln) * 64 + ks * 32 + q * 8;
            short8 bh = *(const short8*)(whi_m + off);
            short8 bl = *(const short8*)(wlo_m + off);
            acc[nt] = __builtin_amdgcn_mfma_f32_16x16x32_bf16(ah[ks], bh, acc[nt], 0, 0, 0);
            acc[nt] = __builtin_amdgcn_mfma_f32_16x16x32_bf16(al[ks], bh, acc[nt], 0, 0, 0);
            acc[nt] = __builtin_amdgcn_mfma_f32_16x16x32_bf16(ah[ks], bl, acc[nt], 0, 0, 0);
        }
    }
    #pragma unroll
    for (int nt = 0; nt < 4; nt++)
        #pragma unroll
        for (int r = 0; r < 4; r++)
            hxb[(m0 + q * 4 + r) * 64 + nt * 16 + ln] = f2bf(acc[nt][r]);
}

// ================= edge aggregation: 8 edges/iter, nearest-bin bf16 table ======
// lane = e8*8 + c8; lane handles edge (base+e8), channels c8*8..+7
__global__ __launch_bounds__(256) void k_edge_agg(const int2* __restrict__ spayload,
                                                  const int* __restrict__ offsets,
                                                  const ushort* __restrict__ hxb,
                                                  const ushort* __restrict__ tblb_t,
                                                  float* __restrict__ agg) {
    int wave = threadIdx.x >> 6, lane = threadIdx.x & 63;
    int n = blockIdx.x * 4 + wave;
    if (n >= NA) return;
    int e8 = lane >> 3, c8 = lane & 7;
    int start = offsets[n], end = offsets[n + 1];
    float acc[8];
    #pragma unroll
    for (int i = 0; i < 8; i++) acc[i] = 0.f;
    for (int base = start; base < end; base += 8) {
        int e = base + e8;
        bool valid = e < end;
        int2 p = spayload[valid ? e : end - 1];
        int srcn = p.x & 0x1FFFF;
        int b = p.y;
        uint4 wv = *(const uint4*)(tblb_t + ((size_t)b << 6) + (c8 << 3));
        uint4 hv = *(const uint4*)(hxb + ((size_t)srcn << 6) + (c8 << 3));
        if (!valid) { hv.x = 0u; hv.y = 0u; hv.z = 0u; hv.w = 0u; }
        uint wa[4] = {wv.x, wv.y, wv.z, wv.w};
        uint ha[4] = {hv.x, hv.y, hv.z, hv.w};
        #pragma unroll
        for (int k = 0; k < 4; k++) {
            float w0 = __uint_as_float(wa[k] << 16);
            float w1 = __uint_as_float(wa[k] & 0xffff0000u);
            float h0 = __uint_as_float(ha[k] << 16);
            float h1 = __uint_as_float(ha[k] & 0xffff0000u);
            acc[2 * k]     = fmaf(w0, h0, acc[2 * k]);
            acc[2 * k + 1] = fmaf(w1, h1, acc[2 * k + 1]);
        }
    }
    #pragma unroll
    for (int i = 0; i < 8; i++) {
        acc[i] += __shfl_xor(acc[i], 8);
        acc[i] += __shfl_xor(acc[i], 16);
        acc[i] += __shfl_xor(acc[i], 32);
    }
    if (e8 == 0) {
        *(float4*)(agg + ((size_t)n << 6) + (c8 << 3)) =
            make_float4(acc[0], acc[1], acc[2], acc[3]);
        *(float4*)(agg + ((size_t)n << 6) + (c8 << 3) + 4) =
            make_float4(acc[4], acc[5], acc[6], acc[7]);
    }
}

// ===== h += ssp(agg@cf2+b2)@lin + lb ; fused next hx OR fused graph readout ====
__global__ __launch_bounds__(256) void k_update(const float* __restrict__ agg,
                                                const ushort* __restrict__ whi,
                                                const ushort* __restrict__ wlo,
                                                int mi_cf2, int mi_lin, int mi_next,
                                                const float* __restrict__ cf2b_t,
                                                const float* __restrict__ linb_t,
                                                float* __restrict__ h,
                                                ushort* __restrict__ hxb,
                                                const int* __restrict__ batch,
                                                float* __restrict__ g) {
    __shared__ ushort Thi[4][16][72];
    __shared__ ushort Tlo[4][16][72];
    __shared__ __align__(16) float Hst[4][16][68];
    int wave = threadIdx.x >> 6, lane = threadIdx.x & 63;
    int tile = blockIdx.x * 4 + wave;
    if (tile >= NTILE) return;
    int m0 = tile * 16;
    int q = lane >> 4, ln = lane & 15;

    // ---- stage 1: T = ssp(agg @ cf2 + b2)
    short8 ah[2], al[2];
    #pragma unroll
    for (int ks = 0; ks < 2; ks++)
        mk_frag(agg + (m0 + ln) * 64 + ks * 32 + q * 8, ah[ks], al[ks]);

    floatx4 acc[4];
    #pragma unroll
    for (int nt = 0; nt < 4; nt++) acc[nt] = (floatx4){0.f, 0.f, 0.f, 0.f};

    const ushort* w2h = whi + mi_cf2 * 4096;
    const ushort* w2l = wlo + mi_cf2 * 4096;
    #pragma unroll
    for (int ks = 0; ks < 2; ks++) {
        #pragma unroll
        for (int nt = 0; nt < 4; nt++) {
            int off = (nt * 16 + ln) * 64 + ks * 32 + q * 8;
            short8 bh = *(const short8*)(w2h + off);
            short8 bl = *(const short8*)(w2l + off);
            acc[nt] = __builtin_amdgcn_mfma_f32_16x16x32_bf16(ah[ks], bh, acc[nt], 0, 0, 0);
            acc[nt] = __builtin_amdgcn_mfma_f32_16x16x32_bf16(al[ks], bh, acc[nt], 0, 0, 0);
            acc[nt] = __builtin_amdgcn_mfma_f32_16x16x32_bf16(ah[ks], bl, acc[nt], 0, 0, 0);
        }
    }
    #pragma unroll
    for (int nt = 0; nt < 4; nt++) {
        float bias = cf2b_t[nt * 16 + ln];
        #pragma unroll
        for (int r = 0; r < 4; r++) {
            float v = ssp(acc[nt][r] + bias);
            ushort hi = f2bf(v);
            Thi[wave][q * 4 + r][nt * 16 + ln] = hi;
            Tlo[wave][q * 4 + r][nt * 16 + ln] = (ushort)f2bf(v - bf2f(hi));
        }
    }
    // same-wave LDS producer/consumer: no barrier needed (per-wave region)

    // ---- stage 2: x = T @ lin
    #pragma unroll
    for (int nt = 0; nt < 4; nt++) acc[nt] = (floatx4){0.f, 0.f, 0.f, 0.f};
    const ushort* wlh = whi + mi_lin * 4096;
    const ushort* wll = wlo + mi_lin * 4096;
    #pragma unroll
    for (int ks = 0; ks < 2; ks++) {
        short8 ah2 = *(const short8*)&Thi[wave][ln][ks * 32 + q * 8];
        short8 al2 = *(const short8*)&Tlo[wave][ln][ks * 32 + q * 8];
        #pragma unroll
        for (int nt = 0; nt < 4; nt++) {
            int off = (nt * 16 + ln) * 64 + ks * 32 + q * 8;
            short8 bh = *(const short8*)(wlh + off);
            short8 bl = *(const short8*)(wll + off);
            acc[nt] = __builtin_amdgcn_mfma_f32_16x16x32_bf16(ah2, bh, acc[nt], 0, 0, 0);
            acc[nt] = __builtin_amdgcn_mfma_f32_16x16x32_bf16(al2, bh, acc[nt], 0, 0, 0);
            acc[nt] = __builtin_amdgcn_mfma_f32_16x16x32_bf16(ah2, bl, acc[nt], 0, 0, 0);
        }
    }

    if (mi_next >= 0) {
        // ---- not last: hnew = h + x + lb -> h, Hst; then next-layer hx
        #pragma unroll
        for (int nt = 0; nt < 4; nt++) {
            float bias = linb_t[nt * 16 + ln];
            #pragma unroll
            for (int r = 0; r < 4; r++) {
                int idx = (m0 + q * 4 + r) * 64 + nt * 16 + ln;
                float hn = h[idx] + acc[nt][r] + bias;
                h[idx] = hn;
                Hst[wave][q * 4 + r][nt * 16 + ln] = hn;
            }
        }
        short8 ah3[2], al3[2];
        #pragma unroll
        for (int ks = 0; ks < 2; ks++)
            mk_frag(&Hst[wave][ln][ks * 32 + q * 8], ah3[ks], al3[ks]);
        #pragma unroll
        for (int nt = 0; nt < 4; nt++) acc[nt] = (floatx4){0.f, 0.f, 0.f, 0.f};
        const ushort* wnh = whi + mi_next * 4096;
        const ushort* wnl = wlo + mi_next * 4096;
        #pragma unroll
        for (int ks = 0; ks < 2; ks++) {
            #pragma unroll
            for (int nt = 0; nt < 4; nt++) {
                int off = (nt * 16 + ln) * 64 + ks * 32 + q * 8;
                short8 bh = *(const short8*)(wnh + off);
                short8 bl = *(const short8*)(wnl + off);
                acc[nt] = __builtin_amdgcn_mfma_f32_16x16x32_bf16(ah3[ks], bh, acc[nt], 0, 0, 0);
                acc[nt] = __builtin_amdgcn_mfma_f32_16x16x32_bf16(al3[ks], bh, acc[nt], 0, 0, 0);
                acc[nt] = __builtin_amdgcn_mfma_f32_16x16x32_bf16(ah3[ks], bl, acc[nt], 0, 0, 0);
            }
        }
        #pragma unroll
        for (int nt = 0; nt < 4; nt++)
            #pragma unroll
            for (int r = 0; r < 4; r++)
                hxb[(m0 + q * 4 + r) * 64 + nt * 16 + ln] = f2bf(acc[nt][r]);
    } else {
        // ---- last interaction: fuse graph readout. hn never stored.
        int b0 = batch[m0], b15 = batch[m0 + 15];
        if (b0 == b15) {
            // homogeneous tile (common: batch sorted, avg graph = 200 atoms)
            #pragma unroll
            for (int nt = 0; nt < 4; nt++) {
                float bias = linb_t[nt * 16 + ln];
                float s = 4.0f * bias;
                #pragma unroll
                for (int r = 0; r < 4; r++) {
                    int idx = (m0 + q * 4 + r) * 64 + nt * 16 + ln;
                    s += h[idx] + acc[nt][r];
                }
                s += __shfl_xor(s, 16);
                s += __shfl_xor(s, 32);
                if (q == 0) atomicAdd(&g[b0 * 64 + nt * 16 + ln], s);
            }
        } else {
            #pragma unroll
            for (int nt = 0; nt < 4; nt++) {
                float bias = linb_t[nt * 16 + ln];
                #pragma unroll
                for (int r = 0; r < 4; r++) {
                    int row = m0 + q * 4 + r;
                    int idx = row * 64 + nt * 16 + ln;
                    atomicAdd(&g[batch[row] * 64 + nt * 16 + ln],
                              h[idx] + acc[nt][r] + bias);
                }
            }
        }
    }
}

// ================= head =================
__global__ __launch_bounds__(64) void k_head(const float* __restrict__ g,
                                             const float* __restrict__ o1w,
                                             const float* __restrict__ o1b,
                                             const float* __restrict__ o2w,
                                             const float* __restrict__ o2b,
                                             float* __restrict__ out) {
    int gi = blockIdx.x;
    int lane = threadIdx.x;
    float gv = g[gi * 64 + lane];
    float a = (lane < 32) ? o1b[lane] : 0.f;
    for (int k = 0; k < 64; k++) {
        float w = (lane < 32) ? o1w[k * 32 + lane] : 0.f;
        a = fmaf(__shfl(gv, k), w, a);
    }
    a = fmaxf(a, 0.f);
    float contrib = (lane < 32) ? a * o2w[lane] : 0.f;
    for (int off = 32; off > 0; off >>= 1) contrib += __shfl_down(contrib, off);
    if (lane == 0) out[gi] = contrib + o2b[0];
}

extern "C" void kernel_launch(void* const* d_in, const int* in_sizes, int n_in,
                              void* d_out, int out_size, void* d_ws, size_t ws_size,
                              hipStream_t stream) {
    (void)in_sizes; (void)n_in; (void)out_size; (void)ws_size;
    const int*   z    = (const int*)d_in[0];
    const float* pos  = (const float*)d_in[1];
    const int*   batch= (const int*)d_in[2];
    const int*   ei   = (const int*)d_in[3];
    const float* emb  = (const float*)d_in[4];
    const float* mw1  = (const float*)d_in[5];
    const float* mb1  = (const float*)d_in[6];
    const float* mw2  = (const float*)d_in[7];
    const float* mb2  = (const float*)d_in[8];
    const float* cf1w = (const float*)d_in[9];
    const float* cf2w = (const float*)d_in[10];
    const float* cf2b = (const float*)d_in[11];
    const float* linw = (const float*)d_in[12];
    const float* linb = (const float*)d_in[13];
    const float* o1w  = (const float*)d_in[14];
    const float* o1b  = (const float*)d_in[15];
    const float* o2w  = (const float*)d_in[16];
    const float* o2b  = (const float*)d_in[17];
    float* out = (float*)d_out;

    char* w = (char*)d_ws;
    auto take = [&](size_t bytes) {
        char* p = w;
        w += (bytes + 255) & ~size_t(255);
        return p;
    };
    int*    hist1    = (int*)take(NBKT * 4);
    int*    offsets1 = (int*)take((NBKT + 1) * 4);
    int*    gcursor1 = (int*)take(NBKT * 4);
    int*    offsets  = (int*)take((NA + 1) * 4);
    int2*   brec     = (int2*)take((size_t)NE * 8);
    int2*   spayload = (int2*)take((size_t)NE * 8);
    ushort* tblb     = (ushort*)take((size_t)NB * NBINS * HD * 2);
    ushort* whi      = (ushort*)take(9 * 4096 * 2);
    ushort* wlo      = (ushort*)take(9 * 4096 * 2);
    float*  h        = (float*)take((size_t)NA * HD * 4);
    ushort* hxb      = (ushort*)take((size_t)NA * HD * 2);
    float*  agg      = (float*)take((size_t)NA * HD * 4);
    float*  g        = (float*)take((size_t)NGR * HD * 4);

    hipMemsetAsync(hist1, 0, NBKT * 4, stream);
    hipMemsetAsync(g, 0, NGR * HD * 4, stream);

    k_count<<<S1_NB, 1024, 0, stream>>>(ei, hist1);
    k_scan196<<<1, 256, 0, stream>>>(hist1, offsets1, gcursor1, offsets);
    k_sort1<<<S1_NB, 1024, 0, stream>>>(ei, pos, gcursor1, brec);
    k_sort2<<<NBKT, 1024, 0, stream>>>(brec, offsets1, spayload, offsets);
    k_table<<<NB * NBINS, 64, 0, stream>>>(mw1, mb1, mw2, mb2, tblb);
    k_wprep<<<(9 * 4096 + 255) / 256, 256, 0, stream>>>(cf1w, cf2w, linw, whi, wlo);
    k_hx0<<<MM_NB, 256, 0, stream>>>(z, emb, whi, wlo, h, hxb);

    int nodeBlocks = (NA + 3) / 4;
    for (int t = 0; t < NB; t++) {
        k_edge_agg<<<nodeBlocks, 256, 0, stream>>>(spayload, offsets, hxb,
                                                   tblb + (size_t)t * NBINS * HD, agg);
        int mi_next = (t < NB - 1) ? ((t + 1) * 3 + 0) : -1;
        k_update<<<MM_NB, 256, 0, stream>>>(agg, whi, wlo, t * 3 + 1, t * 3 + 2, mi_next,
                                            cf2b + t * 64, linb + t * 64, h, hxb,
                                            batch, g);
    }
    k_head<<<NGR, 64, 0, stream>>>(g, o1w, o1b, o2w, o2b, out);
}

// Round 7
// 397.303 us; speedup vs baseline: 3.0323x; 1.0598x over previous
//
#include <hip/hip_runtime.h>
#include <math.h>

constexpr int NA = 50000;
constexpr int NE = 1600000;
constexpr int NGR = 250;
constexpr int HD = 64;
constexpr int NGAUSS = 50;
constexpr int NB = 3;
constexpr float FCUTOFF = 10.0f;

constexpr int NBINS = 16384;                        // nearest-bin table
constexpr float TBL_MAX = 8.6603f;                  // > 5*sqrt(3)
constexpr float TBL_STEP = TBL_MAX / NBINS;

constexpr int NBKT = (NA + 255) / 256;              // 196
constexpr int S1_EPB = 4096;
constexpr int S1_NB = (NE + S1_EPB - 1) / S1_EPB;   // 391

constexpr int NTILE = NA / 16;                      // 3125 (exact)
constexpr int MM_NB = (NTILE + 3) / 4;              // 782
constexpr int NMAT = 15;                            // 9 cf + 3 w1^T + 3 w2^T

typedef __attribute__((ext_vector_type(8))) short short8;
typedef __attribute__((ext_vector_type(4))) float floatx4;
typedef unsigned int uint;
typedef unsigned short ushort;

__device__ __forceinline__ float ssp(float v) {
    return fmaxf(v, 0.f) + log1pf(expf(-fabsf(v))) - 0.69314718055994530942f;
}
__device__ __forceinline__ ushort f2bf(float f) {
    uint u = __float_as_uint(f);
    return (ushort)((u + 0x7fffu + ((u >> 16) & 1u)) >> 16);   // RNE
}
__device__ __forceinline__ float bf2f(ushort h) {
    return __uint_as_float(((uint)h) << 16);
}

// ================= sort pipeline =================
__global__ __launch_bounds__(1024) void k_count(const int* __restrict__ ei,
                                                int* __restrict__ hist1) {
    __shared__ int lh[NBKT];
    for (int i = threadIdx.x; i < NBKT; i += 1024) lh[i] = 0;
    __syncthreads();
    int base = blockIdx.x * S1_EPB;
    #pragma unroll
    for (int i = 0; i < 4; i++) {
        int e = base + i * 1024 + threadIdx.x;
        if (e < NE) atomicAdd(&lh[ei[NE + e] >> 8], 1);
    }
    __syncthreads();
    for (int i = threadIdx.x; i < NBKT; i += 1024)
        if (lh[i]) atomicAdd(&hist1[i], lh[i]);
}

__global__ __launch_bounds__(256) void k_scan196(const int* __restrict__ hist1,
                                                 int* __restrict__ offsets1,
                                                 int* __restrict__ gcursor1,
                                                 int* __restrict__ offsets) {
    __shared__ int buf[256];
    int tid = threadIdx.x;
    int v = (tid < NBKT) ? hist1[tid] : 0;
    buf[tid] = v;
    __syncthreads();
    for (int off = 1; off < 256; off <<= 1) {
        int t = (tid >= off) ? buf[tid - off] : 0;
        __syncthreads();
        buf[tid] += t;
        __syncthreads();
    }
    int excl = buf[tid] - v;
    if (tid < NBKT) { offsets1[tid] = excl; gcursor1[tid] = excl; }
    if (tid == NBKT - 1) offsets1[NBKT] = excl + v;
    if (tid == 0) offsets[NA] = NE;
}

__global__ __launch_bounds__(1024) void k_sort1(const int* __restrict__ ei,
                                                const float* __restrict__ pos,
                                                int* __restrict__ gcursor1,
                                                int2* __restrict__ brec) {
    __shared__ int2 recs[S1_EPB];
    __shared__ unsigned char rbkt[S1_EPB];
    __shared__ int hist[NBKT];
    __shared__ int lcur[NBKT];
    __shared__ int delta[NBKT];
    __shared__ int scanbuf[256];
    int tid = threadIdx.x;
    for (int i = tid; i < NBKT; i += 1024) hist[i] = 0;
    __syncthreads();
    int2 myrec[4];
    int mybkt[4];
    int base = blockIdx.x * S1_EPB;
    #pragma unroll
    for (int i = 0; i < 4; i++) {
        int e = base + i * 1024 + tid;
        mybkt[i] = -1;
        if (e < NE) {
            int s = ei[e];
            int dt = ei[NE + e];
            float dx = pos[dt * 3 + 0] - pos[s * 3 + 0];
            float dy = pos[dt * 3 + 1] - pos[s * 3 + 1];
            float dz = pos[dt * 3 + 2] - pos[s * 3 + 2];
            float d = sqrtf(dx * dx + dy * dy + dz * dz);
            int bin = (int)(d * (1.0f / TBL_STEP) + 0.5f);
            bin = min(bin, NBINS - 1);
            myrec[i] = make_int2(s | ((dt & 255) << 17), bin);
            mybkt[i] = dt >> 8;
            atomicAdd(&hist[mybkt[i]], 1);
        }
    }
    __syncthreads();
    int v = (tid < NBKT) ? hist[tid] : 0;
    if (tid < 256) scanbuf[tid] = v;
    __syncthreads();
    for (int off = 1; off < 256; off <<= 1) {
        int t = (tid >= off && tid < 256) ? scanbuf[tid - off] : 0;
        __syncthreads();
        if (tid < 256) scanbuf[tid] += t;
        __syncthreads();
    }
    if (tid < NBKT) {
        int excl = scanbuf[tid] - v;
        lcur[tid] = excl;
        int gbase = atomicAdd(&gcursor1[tid], v);
        delta[tid] = gbase - excl;
    }
    __syncthreads();
    #pragma unroll
    for (int i = 0; i < 4; i++) {
        if (mybkt[i] >= 0) {
            int r = atomicAdd(&lcur[mybkt[i]], 1);
            recs[r] = myrec[i];
            rbkt[r] = (unsigned char)mybkt[i];
        }
    }
    __syncthreads();
    int total = min(S1_EPB, NE - base);
    for (int p = tid; p < total; p += 1024)
        brec[delta[rbkt[p]] + p] = recs[p];
}

// writes packed payload: src(16) | bin(14)<<16
__global__ __launch_bounds__(1024) void k_sort2(const int2* __restrict__ brec,
                                                const int* __restrict__ offsets1,
                                                uint* __restrict__ spayload,
                                                int* __restrict__ offsets) {
    __shared__ int cnt[256];
    __shared__ int lstart[256];
    __shared__ int lcur[256];
    int b = blockIdx.x;
    int tid = threadIdx.x;
    if (tid < 256) cnt[tid] = 0;
    __syncthreads();
    int rbase = offsets1[b], rend = offsets1[b + 1];
    for (int p = rbase + tid; p < rend; p += 1024)
        atomicAdd(&cnt[(brec[p].x >> 17) & 255], 1);
    __syncthreads();
    int v = (tid < 256) ? cnt[tid] : 0;
    if (tid < 256) lstart[tid] = v;
    __syncthreads();
    for (int off = 1; off < 256; off <<= 1) {
        int t = (tid >= off && tid < 256) ? lstart[tid - off] : 0;
        __syncthreads();
        if (tid < 256) lstart[tid] += t;
        __syncthreads();
    }
    if (tid < 256) {
        lstart[tid] -= v;
        lcur[tid] = rbase + lstart[tid];
        int node = (b << 8) + tid;
        if (node < NA) offsets[node] = rbase + lstart[tid];
    }
    __syncthreads();
    for (int p = rbase + tid; p < rend; p += 1024) {
        int2 r = brec[p];
        int slot = atomicAdd(&lcur[(r.x >> 17) & 255], 1);
        spayload[slot] = (uint)(r.x & 0xFFFF) | ((uint)r.y << 16);
    }
}

// ====== weight prep: bf16 hi/lo, B-fragment order [mat][n][k] ======
// mats 0..8: cf1/cf2/lin per t ; 9..11: w1^T (k=gauss, zero-padded 50->64) ; 12..14: w2^T
__global__ __launch_bounds__(256) void k_wprep(const float* __restrict__ cf1w,
                                               const float* __restrict__ cf2w,
                                               const float* __restrict__ linw,
                                               const float* __restrict__ mw1,
                                               const float* __restrict__ mw2,
                                               ushort* __restrict__ whi,
                                               ushort* __restrict__ wlo) {
    int idx = blockIdx.x * 256 + threadIdx.x;
    if (idx >= NMAT * 4096) return;
    int mi = idx >> 12;
    int rem = idx & 4095;
    int n = rem >> 6, k = rem & 63;
    float v;
    if (mi < 9) {
        int t = mi / 3, which = mi % 3;
        const float* src = (which == 0) ? cf1w : (which == 1) ? cf2w : linw;
        v = src[t * 4096 + k * 64 + n];
    } else if (mi < 12) {
        int t = mi - 9;
        v = (k < NGAUSS) ? mw1[(t * NGAUSS + k) * 64 + n] : 0.f;
    } else {
        int t = mi - 12;
        v = mw2[t * 4096 + k * 64 + n];
    }
    ushort hi = f2bf(v);
    ushort lo = f2bf(v - bf2f(hi));
    whi[mi * 4096 + n * 64 + k] = hi;
    wlo[mi * 4096 + n * 64 + k] = lo;
}

// ================= Wf table via MFMA: 16 bins/wave, two-stage MLP =================
__global__ __launch_bounds__(256) void k_table(const ushort* __restrict__ whi,
                                               const ushort* __restrict__ wlo,
                                               const float* __restrict__ b1,
                                               const float* __restrict__ b2,
                                               ushort* __restrict__ tblb) {
    __shared__ ushort Thi[4][16][72];
    __shared__ ushort Tlo[4][16][72];
    int wave = threadIdx.x >> 6, lane = threadIdx.x & 63;
    constexpr int TPB = NBINS / 16;     // 1024 tiles per t
    int tile = blockIdx.x * 4 + wave;   // 3072 total
    int t = tile / TPB;
    int bin0 = (tile % TPB) * 16;
    int q = lane >> 4, ln = lane & 15;
    const float spacing = FCUTOFF / (NGAUSS - 1);
    const float coeff = -0.5f / (spacing * spacing);
    float d_ln = (bin0 + ln) * TBL_STEP;

    // A-fragment: rbf[m=ln][k = ks*32 + q*8 + j], zero for k >= NGAUSS
    short8 ah[2], al[2];
    #pragma unroll
    for (int ks = 0; ks < 2; ks++) {
        #pragma unroll
        for (int j = 0; j < 8; j++) {
            int gg = ks * 32 + q * 8 + j;
            float u = d_ln - gg * spacing;
            float r = (gg < NGAUSS) ? expf(coeff * u * u) : 0.f;
            ushort hh = f2bf(r);
            ah[ks][j] = (short)hh;
            al[ks][j] = (short)f2bf(r - bf2f(hh));
        }
    }
    floatx4 acc[4];
    #pragma unroll
    for (int nt = 0; nt < 4; nt++) acc[nt] = (floatx4){0.f, 0.f, 0.f, 0.f};
    const ushort* w1h = whi + (9 + t) * 4096;
    const ushort* w1l = wlo + (9 + t) * 4096;
    #pragma unroll
    for (int ks = 0; ks < 2; ks++) {
        #pragma unroll
        for (int nt = 0; nt < 4; nt++) {
            int off = (nt * 16 + ln) * 64 + ks * 32 + q * 8;
            short8 bh = *(const short8*)(w1h + off);
            short8 bl = *(const short8*)(w1l + off);
            acc[nt] = __builtin_amdgcn_mfma_f32_16x16x32_bf16(ah[ks], bh, acc[nt], 0, 0, 0);
            acc[nt] = __builtin_amdgcn_mfma_f32_16x16x32_bf16(al[ks], bh, acc[nt], 0, 0, 0);
            acc[nt] = __builtin_amdgcn_mfma_f32_16x16x32_bf16(ah[ks], bl, acc[nt], 0, 0, 0);
        }
    }
    #pragma unroll
    for (int nt = 0; nt < 4; nt++) {
        float bias = b1[t * 64 + nt * 16 + ln];
        #pragma unroll
        for (int r = 0; r < 4; r++) {
            float v = ssp(acc[nt][r] + bias);
            ushort hi = f2bf(v);
            Thi[wave][q * 4 + r][nt * 16 + ln] = hi;
            Tlo[wave][q * 4 + r][nt * 16 + ln] = (ushort)f2bf(v - bf2f(hi));
        }
    }
    // same-wave LDS round trip; no barrier needed
    #pragma unroll
    for (int nt = 0; nt < 4; nt++) acc[nt] = (floatx4){0.f, 0.f, 0.f, 0.f};
    const ushort* w2h = whi + (12 + t) * 4096;
    const ushort* w2l = wlo + (12 + t) * 4096;
    #pragma unroll
    for (int ks = 0; ks < 2; ks++) {
        short8 ah2 = *(const short8*)&Thi[wave][ln][ks * 32 + q * 8];
        short8 al2 = *(const short8*)&Tlo[wave][ln][ks * 32 + q * 8];
        #pragma unroll
        for (int nt = 0; nt < 4; nt++) {
            int off = (nt * 16 + ln) * 64 + ks * 32 + q * 8;
            short8 bh = *(const short8*)(w2h + off);
            short8 bl = *(const short8*)(w2l + off);
            acc[nt] = __builtin_amdgcn_mfma_f32_16x16x32_bf16(ah2, bh, acc[nt], 0, 0, 0);
            acc[nt] = __builtin_amdgcn_mfma_f32_16x16x32_bf16(al2, bh, acc[nt], 0, 0, 0);
            acc[nt] = __builtin_amdgcn_mfma_f32_16x16x32_bf16(ah2, bl, acc[nt], 0, 0, 0);
        }
    }
    #pragma unroll
    for (int nt = 0; nt < 4; nt++) {
        float bias = b2[t * 64 + nt * 16 + ln];
        #pragma unroll
        for (int r = 0; r < 4; r++) {
            int bin = bin0 + q * 4 + r;
            float d = bin * TBL_STEP;
            float C = 0.5f * (cosf(d * (float)M_PI / FCUTOFF) + 1.0f);
            tblb[(t * NBINS + bin) * 64 + nt * 16 + ln] = f2bf((acc[nt][r] + bias) * C);
        }
    }
}

__device__ __forceinline__ void mk_frag2(float4 a0, float4 a1, short8& hi, short8& lo) {
    float av[8] = {a0.x, a0.y, a0.z, a0.w, a1.x, a1.y, a1.z, a1.w};
    #pragma unroll
    for (int j = 0; j < 8; j++) {
        ushort h = f2bf(av[j]);
        hi[j] = (short)h;
        lo[j] = (short)f2bf(av[j] - bf2f(h));
    }
}
__device__ __forceinline__ void mk_frag(const float* p, short8& hi, short8& lo) {
    mk_frag2(*(const float4*)p, *(const float4*)(p + 4), hi, lo);
}

// ================= fused h-init + first hx =================
__global__ __launch_bounds__(256) void k_hx0(const int* __restrict__ z,
                                             const float* __restrict__ emb,
                                             const ushort* __restrict__ whi_m,
                                             const ushort* __restrict__ wlo_m,
                                             float* __restrict__ h,
                                             ushort* __restrict__ hxb) {
    int wave = threadIdx.x >> 6, lane = threadIdx.x & 63;
    int tile = blockIdx.x * 4 + wave;
    if (tile >= NTILE) return;
    int m0 = tile * 16;
    int q = lane >> 4, ln = lane & 15;
    int row = m0 + ln;
    int zr = z[row];

    short8 ah[2], al[2];
    #pragma unroll
    for (int ks = 0; ks < 2; ks++) {
        float4 a0 = *(const float4*)(emb + zr * 64 + ks * 32 + q * 8);
        float4 a1 = *(const float4*)(emb + zr * 64 + ks * 32 + q * 8 + 4);
        *(float4*)(h + (size_t)row * 64 + ks * 32 + q * 8) = a0;
        *(float4*)(h + (size_t)row * 64 + ks * 32 + q * 8 + 4) = a1;
        mk_frag2(a0, a1, ah[ks], al[ks]);
    }
    floatx4 acc[4];
    #pragma unroll
    for (int nt = 0; nt < 4; nt++) acc[nt] = (floatx4){0.f, 0.f, 0.f, 0.f};
    #pragma unroll
    for (int ks = 0; ks < 2; ks++) {
        #pragma unroll
        for (int nt = 0; nt < 4; nt++) {
            int off = (nt * 16 + ln) * 64 + ks * 32 + q * 8;
            short8 bh = *(const short8*)(whi_m + off);
            short8 bl = *(const short8*)(wlo_m + off);
            acc[nt] = __builtin_amdgcn_mfma_f32_16x16x32_bf16(ah[ks], bh, acc[nt], 0, 0, 0);
            acc[nt] = __builtin_amdgcn_mfma_f32_16x16x32_bf16(al[ks], bh, acc[nt], 0, 0, 0);
            acc[nt] = __builtin_amdgcn_mfma_f32_16x16x32_bf16(ah[ks], bl, acc[nt], 0, 0, 0);
        }
    }
    #pragma unroll
    for (int nt = 0; nt < 4; nt++)
        #pragma unroll
        for (int r = 0; r < 4; r++)
            hxb[(m0 + q * 4 + r) * 64 + nt * 16 + ln] = f2bf(acc[nt][r]);
}

// ================= edge aggregation: 8 edges/iter, packed 4B payload ======
__global__ __launch_bounds__(256) void k_edge_agg(const uint* __restrict__ spayload,
                                                  const int* __restrict__ offsets,
                                                  const ushort* __restrict__ hxb,
                                                  const ushort* __restrict__ tblb_t,
                                                  float* __restrict__ agg) {
    int wave = threadIdx.x >> 6, lane = threadIdx.x & 63;
    int n = blockIdx.x * 4 + wave;
    if (n >= NA) return;
    int e8 = lane >> 3, c8 = lane & 7;
    int start = offsets[n], end = offsets[n + 1];
    float acc[8];
    #pragma unroll
    for (int i = 0; i < 8; i++) acc[i] = 0.f;
    for (int base = start; base < end; base += 8) {
        int e = base + e8;
        bool valid = e < end;
        uint p = spayload[valid ? e : end - 1];
        int srcn = p & 0xFFFF;
        int b = p >> 16;
        uint4 wv = *(const uint4*)(tblb_t + ((size_t)b << 6) + (c8 << 3));
        uint4 hv = *(const uint4*)(hxb + ((size_t)srcn << 6) + (c8 << 3));
        if (!valid) { hv.x = 0u; hv.y = 0u; hv.z = 0u; hv.w = 0u; }
        uint wa[4] = {wv.x, wv.y, wv.z, wv.w};
        uint ha[4] = {hv.x, hv.y, hv.z, hv.w};
        #pragma unroll
        for (int k = 0; k < 4; k++) {
            float w0 = __uint_as_float(wa[k] << 16);
            float w1 = __uint_as_float(wa[k] & 0xffff0000u);
            float h0 = __uint_as_float(ha[k] << 16);
            float h1 = __uint_as_float(ha[k] & 0xffff0000u);
            acc[2 * k]     = fmaf(w0, h0, acc[2 * k]);
            acc[2 * k + 1] = fmaf(w1, h1, acc[2 * k + 1]);
        }
    }
    #pragma unroll
    for (int i = 0; i < 8; i++) {
        acc[i] += __shfl_xor(acc[i], 8);
        acc[i] += __shfl_xor(acc[i], 16);
        acc[i] += __shfl_xor(acc[i], 32);
    }
    if (e8 == 0) {
        *(float4*)(agg + ((size_t)n << 6) + (c8 << 3)) =
            make_float4(acc[0], acc[1], acc[2], acc[3]);
        *(float4*)(agg + ((size_t)n << 6) + (c8 << 3) + 4) =
            make_float4(acc[4], acc[5], acc[6], acc[7]);
    }
}

// ===== h += ssp(agg@cf2+b2)@lin + lb ; fused next hx OR fused graph readout ====
__global__ __launch_bounds__(256) void k_update(const float* __restrict__ agg,
                                                const ushort* __restrict__ whi,
                                                const ushort* __restrict__ wlo,
                                                int mi_cf2, int mi_lin, int mi_next,
                                                const float* __restrict__ cf2b_t,
                                                const float* __restrict__ linb_t,
                                                float* __restrict__ h,
                                                ushort* __restrict__ hxb,
                                                const int* __restrict__ batch,
                                                float* __restrict__ g) {
    __shared__ ushort Thi[4][16][72];
    __shared__ ushort Tlo[4][16][72];
    __shared__ __align__(16) float Hst[4][16][68];
    int wave = threadIdx.x >> 6, lane = threadIdx.x & 63;
    int tile = blockIdx.x * 4 + wave;
    if (tile >= NTILE) return;
    int m0 = tile * 16;
    int q = lane >> 4, ln = lane & 15;

    short8 ah[2], al[2];
    #pragma unroll
    for (int ks = 0; ks < 2; ks++)
        mk_frag(agg + (m0 + ln) * 64 + ks * 32 + q * 8, ah[ks], al[ks]);

    floatx4 acc[4];
    #pragma unroll
    for (int nt = 0; nt < 4; nt++) acc[nt] = (floatx4){0.f, 0.f, 0.f, 0.f};

    const ushort* w2h = whi + mi_cf2 * 4096;
    const ushort* w2l = wlo + mi_cf2 * 4096;
    #pragma unroll
    for (int ks = 0; ks < 2; ks++) {
        #pragma unroll
        for (int nt = 0; nt < 4; nt++) {
            int off = (nt * 16 + ln) * 64 + ks * 32 + q * 8;
            short8 bh = *(const short8*)(w2h + off);
            short8 bl = *(const short8*)(w2l + off);
            acc[nt] = __builtin_amdgcn_mfma_f32_16x16x32_bf16(ah[ks], bh, acc[nt], 0, 0, 0);
            acc[nt] = __builtin_amdgcn_mfma_f32_16x16x32_bf16(al[ks], bh, acc[nt], 0, 0, 0);
            acc[nt] = __builtin_amdgcn_mfma_f32_16x16x32_bf16(ah[ks], bl, acc[nt], 0, 0, 0);
        }
    }
    #pragma unroll
    for (int nt = 0; nt < 4; nt++) {
        float bias = cf2b_t[nt * 16 + ln];
        #pragma unroll
        for (int r = 0; r < 4; r++) {
            float v = ssp(acc[nt][r] + bias);
            ushort hi = f2bf(v);
            Thi[wave][q * 4 + r][nt * 16 + ln] = hi;
            Tlo[wave][q * 4 + r][nt * 16 + ln] = (ushort)f2bf(v - bf2f(hi));
        }
    }

    #pragma unroll
    for (int nt = 0; nt < 4; nt++) acc[nt] = (floatx4){0.f, 0.f, 0.f, 0.f};
    const ushort* wlh = whi + mi_lin * 4096;
    const ushort* wll = wlo + mi_lin * 4096;
    #pragma unroll
    for (int ks = 0; ks < 2; ks++) {
        short8 ah2 = *(const short8*)&Thi[wave][ln][ks * 32 + q * 8];
        short8 al2 = *(const short8*)&Tlo[wave][ln][ks * 32 + q * 8];
        #pragma unroll
        for (int nt = 0; nt < 4; nt++) {
            int off = (nt * 16 + ln) * 64 + ks * 32 + q * 8;
            short8 bh = *(const short8*)(wlh + off);
            short8 bl = *(const short8*)(wll + off);
            acc[nt] = __builtin_amdgcn_mfma_f32_16x16x32_bf16(ah2, bh, acc[nt], 0, 0, 0);
            acc[nt] = __builtin_amdgcn_mfma_f32_16x16x32_bf16(al2, bh, acc[nt], 0, 0, 0);
            acc[nt] = __builtin_amdgcn_mfma_f32_16x16x32_bf16(ah2, bl, acc[nt], 0, 0, 0);
        }
    }

    if (mi_next >= 0) {
        #pragma unroll
        for (int nt = 0; nt < 4; nt++) {
            float bias = linb_t[nt * 16 + ln];
            #pragma unroll
            for (int r = 0; r < 4; r++) {
                int idx = (m0 + q * 4 + r) * 64 + nt * 16 + ln;
                float hn = h[idx] + acc[nt][r] + bias;
                h[idx] = hn;
                Hst[wave][q * 4 + r][nt * 16 + ln] = hn;
            }
        }
        short8 ah3[2], al3[2];
        #pragma unroll
        for (int ks = 0; ks < 2; ks++)
            mk_frag(&Hst[wave][ln][ks * 32 + q * 8], ah3[ks], al3[ks]);
        #pragma unroll
        for (int nt = 0; nt < 4; nt++) acc[nt] = (floatx4){0.f, 0.f, 0.f, 0.f};
        const ushort* wnh = whi + mi_next * 4096;
        const ushort* wnl = wlo + mi_next * 4096;
        #pragma unroll
        for (int ks = 0; ks < 2; ks++) {
            #pragma unroll
            for (int nt = 0; nt < 4; nt++) {
                int off = (nt * 16 + ln) * 64 + ks * 32 + q * 8;
                short8 bh = *(const short8*)(wnh + off);
                short8 bl = *(const short8*)(wnl + off);
                acc[nt] = __builtin_amdgcn_mfma_f32_16x16x32_bf16(ah3[ks], bh, acc[nt], 0, 0, 0);
                acc[nt] = __builtin_amdgcn_mfma_f32_16x16x32_bf16(al3[ks], bh, acc[nt], 0, 0, 0);
                acc[nt] = __builtin_amdgcn_mfma_f32_16x16x32_bf16(ah3[ks], bl, acc[nt], 0, 0, 0);
            }
        }
        #pragma unroll
        for (int nt = 0; nt < 4; nt++)
            #pragma unroll
            for (int r = 0; r < 4; r++)
                hxb[(m0 + q * 4 + r) * 64 + nt * 16 + ln] = f2bf(acc[nt][r]);
    } else {
        int b0 = batch[m0], b15 = batch[m0 + 15];
        if (b0 == b15) {
            #pragma unroll
            for (int nt = 0; nt < 4; nt++) {
                float bias = linb_t[nt * 16 + ln];
                float s = 4.0f * bias;
                #pragma unroll
                for (int r = 0; r < 4; r++) {
                    int idx = (m0 + q * 4 + r) * 64 + nt * 16 + ln;
                    s += h[idx] + acc[nt][r];
                }
                s += __shfl_xor(s, 16);
                s += __shfl_xor(s, 32);
                if (q == 0) atomicAdd(&g[b0 * 64 + nt * 16 + ln], s);
            }
        } else {
            #pragma unroll
            for (int nt = 0; nt < 4; nt++) {
                float bias = linb_t[nt * 16 + ln];
                #pragma unroll
                for (int r = 0; r < 4; r++) {
                    int row = m0 + q * 4 + r;
                    int idx = row * 64 + nt * 16 + ln;
                    atomicAdd(&g[batch[row] * 64 + nt * 16 + ln],
                              h[idx] + acc[nt][r] + bias);
                }
            }
        }
    }
}

// ================= head =================
__global__ __launch_bounds__(64) void k_head(const float* __restrict__ g,
                                             const float* __restrict__ o1w,
                                             const float* __restrict__ o1b,
                                             const float* __restrict__ o2w,
                                             const float* __restrict__ o2b,
                                             float* __restrict__ out) {
    int gi = blockIdx.x;
    int lane = threadIdx.x;
    float gv = g[gi * 64 + lane];
    float a = (lane < 32) ? o1b[lane] : 0.f;
    for (int k = 0; k < 64; k++) {
        float w = (lane < 32) ? o1w[k * 32 + lane] : 0.f;
        a = fmaf(__shfl(gv, k), w, a);
    }
    a = fmaxf(a, 0.f);
    float contrib = (lane < 32) ? a * o2w[lane] : 0.f;
    for (int off = 32; off > 0; off >>= 1) contrib += __shfl_down(contrib, off);
    if (lane == 0) out[gi] = contrib + o2b[0];
}

extern "C" void kernel_launch(void* const* d_in, const int* in_sizes, int n_in,
                              void* d_out, int out_size, void* d_ws, size_t ws_size,
                              hipStream_t stream) {
    (void)in_sizes; (void)n_in; (void)out_size; (void)ws_size;
    const int*   z    = (const int*)d_in[0];
    const float* pos  = (const float*)d_in[1];
    const int*   batch= (const int*)d_in[2];
    const int*   ei   = (const int*)d_in[3];
    const float* emb  = (const float*)d_in[4];
    const float* mw1  = (const float*)d_in[5];
    const float* mb1  = (const float*)d_in[6];
    const float* mw2  = (const float*)d_in[7];
    const float* mb2  = (const float*)d_in[8];
    const float* cf1w = (const float*)d_in[9];
    const float* cf2w = (const float*)d_in[10];
    const float* cf2b = (const float*)d_in[11];
    const float* linw = (const float*)d_in[12];
    const float* linb = (const float*)d_in[13];
    const float* o1w  = (const float*)d_in[14];
    const float* o1b  = (const float*)d_in[15];
    const float* o2w  = (const float*)d_in[16];
    const float* o2b  = (const float*)d_in[17];
    float* out = (float*)d_out;

    char* w = (char*)d_ws;
    auto take = [&](size_t bytes) {
        char* p = w;
        w += (bytes + 255) & ~size_t(255);
        return p;
    };
    int*    hist1    = (int*)take(NBKT * 4);
    int*    offsets1 = (int*)take((NBKT + 1) * 4);
    int*    gcursor1 = (int*)take(NBKT * 4);
    int*    offsets  = (int*)take((NA + 1) * 4);
    int2*   brec     = (int2*)take((size_t)NE * 8);
    uint*   spayload = (uint*)take((size_t)NE * 4);
    ushort* tblb     = (ushort*)take((size_t)NB * NBINS * HD * 2);
    ushort* whi      = (ushort*)take(NMAT * 4096 * 2);
    ushort* wlo      = (ushort*)take(NMAT * 4096 * 2);
    float*  h        = (float*)take((size_t)NA * HD * 4);
    ushort* hxb      = (ushort*)take((size_t)NA * HD * 2);
    float*  agg      = (float*)take((size_t)NA * HD * 4);
    float*  g        = (float*)take((size_t)NGR * HD * 4);

    hipMemsetAsync(hist1, 0, NBKT * 4, stream);
    hipMemsetAsync(g, 0, NGR * HD * 4, stream);

    k_count<<<S1_NB, 1024, 0, stream>>>(ei, hist1);
    k_scan196<<<1, 256, 0, stream>>>(hist1, offsets1, gcursor1, offsets);
    k_sort1<<<S1_NB, 1024, 0, stream>>>(ei, pos, gcursor1, brec);
    k_sort2<<<NBKT, 1024, 0, stream>>>(brec, offsets1, spayload, offsets);
    k_wprep<<<(NMAT * 4096 + 255) / 256, 256, 0, stream>>>(cf1w, cf2w, linw, mw1, mw2,
                                                           whi, wlo);
    k_table<<<NB * (NBINS / 16) / 4, 256, 0, stream>>>(whi, wlo, mb1, mb2, tblb);
    k_hx0<<<MM_NB, 256, 0, stream>>>(z, emb, whi, wlo, h, hxb);

    int nodeBlocks = (NA + 3) / 4;
    for (int t = 0; t < NB; t++) {
        k_edge_agg<<<nodeBlocks, 256, 0, stream>>>(spayload, offsets, hxb,
                                                   tblb + (size_t)t * NBINS * HD, agg);
        int mi_next = (t < NB - 1) ? ((t + 1) * 3 + 0) : -1;
        k_update<<<MM_NB, 256, 0, stream>>>(agg, whi, wlo, t * 3 + 1, t * 3 + 2, mi_next,
                                            cf2b + t * 64, linb + t * 64, h, hxb,
                                            batch, g);
    }
    k_head<<<NGR, 64, 0, stream>>>(g, o1w, o1b, o2w, o2b, out);
}